// Round 1
// baseline (1070.544 us; speedup 1.0000x reference)
//
#include <hip/hip_runtime.h>
#include <hip/hip_bf16.h>

// PPGNN: lift -> 5x (mean-aggregate + Lotka-Volterra Euler step) -> readout
// N=50000, E=800000, C_IN=128, H=96, C_OUT=40, L=5, DT=0.05

#define HDIM 96
#define CIN 128
#define COUT 40
#define NLAYER 5
#define DTC 0.05f

// ---------------- CSR build ----------------

__global__ void count_kernel(const int* __restrict__ dst, int* __restrict__ deg, int E) {
    int e = blockIdx.x * blockDim.x + threadIdx.x;
    if (e < E) atomicAdd(&deg[dst[e]], 1);
}

__global__ void scan_kernel(const int* __restrict__ deg, int* __restrict__ rowptr,
                            float* __restrict__ deg_inv, int N) {
    __shared__ int sdata[1024];
    __shared__ int s_carry;
    if (threadIdx.x == 0) s_carry = 0;
    __syncthreads();
    for (int base = 0; base < N; base += 1024) {
        int i = base + (int)threadIdx.x;
        int v = (i < N) ? deg[i] : 0;
        sdata[threadIdx.x] = v;
        __syncthreads();
        for (int off = 1; off < 1024; off <<= 1) {
            int t = (threadIdx.x >= (unsigned)off) ? sdata[threadIdx.x - off] : 0;
            __syncthreads();
            sdata[threadIdx.x] += t;
            __syncthreads();
        }
        if (i < N) {
            rowptr[i] = s_carry + sdata[threadIdx.x] - v;  // exclusive
            deg_inv[i] = 1.0f / fmaxf((float)v, 1.0f);
        }
        __syncthreads();
        if (threadIdx.x == 0) s_carry += sdata[1023];
        __syncthreads();
    }
    if (threadIdx.x == 0) rowptr[N] = s_carry;
}

__global__ void fill_kernel(const int* __restrict__ src, const int* __restrict__ dst,
                            const int* __restrict__ rowptr, int* __restrict__ fill,
                            int* __restrict__ csr, int E) {
    int e = blockIdx.x * blockDim.x + threadIdx.x;
    if (e < E) {
        int d = dst[e];
        int pos = rowptr[d] + atomicAdd(&fill[d], 1);
        csr[pos] = src[e];
    }
}

// ---------------- Lift: X=tanh(xWx+bx), Y=tanh(xWy+by) ----------------

__global__ void lift_kernel(const float* __restrict__ x,
                            const float* __restrict__ Wx, const float* __restrict__ bx,
                            const float* __restrict__ Wy, const float* __restrict__ by,
                            float* __restrict__ X, float* __restrict__ Y, int N) {
    int tid = blockIdx.x * blockDim.x + threadIdx.x;
    if (tid >= N * HDIM) return;
    int node = tid / HDIM;
    int h = tid - node * HDIM;
    const float* xr = x + (size_t)node * CIN;
    float ax = bx[h], ay = by[h];
#pragma unroll 8
    for (int c = 0; c < CIN; c++) {
        float xv = xr[c];
        ax = fmaf(xv, Wx[c * HDIM + h], ax);
        ay = fmaf(xv, Wy[c * HDIM + h], ay);
    }
    X[tid] = tanhf(ax);
    Y[tid] = tanhf(ay);
}

// ---------------- Layer: mean agg + LV Euler update ----------------
// One wave (64 lanes) per node. Lane handles channel `lane`, and channel
// `64+lane` if lane<32 (H=96 = 64+32).

__global__ void layer_kernel(const float* __restrict__ X, const float* __restrict__ Y,
                             float* __restrict__ Xn, float* __restrict__ Yn,
                             const int* __restrict__ rowptr, const int* __restrict__ csr,
                             const float* __restrict__ deg_inv,
                             const float* __restrict__ alpha, const float* __restrict__ beta,
                             const float* __restrict__ gamma, const float* __restrict__ delta,
                             int N) {
    int wave = threadIdx.x >> 6;
    int lane = threadIdx.x & 63;
    int node = blockIdx.x * 4 + wave;
    if (node >= N) return;

    int beg = rowptr[node];
    int end = rowptr[node + 1];

    float ax0 = 0.f, ax1 = 0.f, ay0 = 0.f, ay1 = 0.f;
    for (int e = beg; e < end; e++) {
        int s = csr[e];
        s = __builtin_amdgcn_readfirstlane(s);  // wave-uniform -> scalar addressing
        const float* xr = X + (size_t)s * HDIM;
        const float* yr = Y + (size_t)s * HDIM;
        ax0 += xr[lane];
        ay0 += yr[lane];
        if (lane < 32) {
            ax1 += xr[64 + lane];
            ay1 += yr[64 + lane];
        }
    }
    float dinv = deg_inv[node];
    ax0 *= dinv; ax1 *= dinv; ay0 *= dinv; ay1 *= dinv;

    size_t base = (size_t)node * HDIM;
    {
        int c = lane;
        float xv = X[base + c], yv = Y[base + c];
        Xn[base + c] = xv + DTC * xv * (alpha[c] - beta[c] * ay0);
        Yn[base + c] = yv + DTC * yv * (-gamma[c] + delta[c] * ax0);
    }
    if (lane < 32) {
        int c = 64 + lane;
        float xv = X[base + c], yv = Y[base + c];
        Xn[base + c] = xv + DTC * xv * (alpha[c] - beta[c] * ay1);
        Yn[base + c] = yv + DTC * yv * (-gamma[c] + delta[c] * ax1);
    }
}

// ---------------- Readout: out = [X,Y] @ Wr + br ----------------
// Block = 256 threads; 6 nodes/block (6*40=240 active lanes for the dot).

#define RO_NODES 6

__global__ void readout_kernel(const float* __restrict__ X, const float* __restrict__ Y,
                               const float* __restrict__ Wr, const float* __restrict__ br,
                               float* __restrict__ out, int N) {
    __shared__ float sW[2 * HDIM * COUT];  // 192*40 = 7680 floats
    __shared__ float sB[COUT];
    __shared__ float sXY[RO_NODES * 2 * HDIM];  // 6*192

    for (int i = threadIdx.x; i < 2 * HDIM * COUT; i += blockDim.x) sW[i] = Wr[i];
    if (threadIdx.x < COUT) sB[threadIdx.x] = br[threadIdx.x];

    int base_node = blockIdx.x * RO_NODES;
    for (int i = threadIdx.x; i < RO_NODES * 2 * HDIM; i += blockDim.x) {
        int li = i / (2 * HDIM);
        int h = i - li * (2 * HDIM);
        int nd = base_node + li;
        float v = 0.f;
        if (nd < N) v = (h < HDIM) ? X[(size_t)nd * HDIM + h] : Y[(size_t)nd * HDIM + (h - HDIM)];
        sXY[i] = v;
    }
    __syncthreads();

    int t = threadIdx.x;
    int li = t / COUT;
    int o = t - li * COUT;
    int node = base_node + li;
    if (li < RO_NODES && node < N) {
        const float* row = &sXY[li * 2 * HDIM];
        float acc = sB[o];
#pragma unroll
        for (int h = 0; h < 2 * HDIM; h++) acc = fmaf(row[h], sW[h * COUT + o], acc);
        out[(size_t)node * COUT + o] = acc;
    }
}

// ---------------- launch ----------------

extern "C" void kernel_launch(void* const* d_in, const int* in_sizes, int n_in,
                              void* d_out, int out_size, void* d_ws, size_t ws_size,
                              hipStream_t stream) {
    const float* x     = (const float*)d_in[0];
    const int*   ei    = (const int*)d_in[1];
    const float* Wx    = (const float*)d_in[2];
    const float* bx    = (const float*)d_in[3];
    const float* Wy    = (const float*)d_in[4];
    const float* by    = (const float*)d_in[5];
    const float* alpha = (const float*)d_in[6];
    const float* beta  = (const float*)d_in[7];
    const float* gamma = (const float*)d_in[8];
    const float* delta = (const float*)d_in[9];
    const float* Wr    = (const float*)d_in[10];
    const float* br    = (const float*)d_in[11];

    const int N = in_sizes[0] / CIN;
    const int E = in_sizes[1] / 2;

    // workspace carve-up (256B aligned)
    char* ws = (char*)d_ws;
    size_t off = 0;
    auto alloc = [&](size_t bytes) -> void* {
        off = (off + 255) & ~(size_t)255;
        void* p = ws + off;
        off += bytes;
        return p;
    };
    int* deg     = (int*)alloc((size_t)2 * N * sizeof(int));  // deg + fill, contiguous
    int* fill    = deg + N;
    int* rowptr  = (int*)alloc((size_t)(N + 1) * sizeof(int));
    int* csr     = (int*)alloc((size_t)E * sizeof(int));
    float* dinv  = (float*)alloc((size_t)N * sizeof(float));
    float* Xa    = (float*)alloc((size_t)N * HDIM * sizeof(float));
    float* Ya    = (float*)alloc((size_t)N * HDIM * sizeof(float));
    float* Xb    = (float*)alloc((size_t)N * HDIM * sizeof(float));
    float* Yb    = (float*)alloc((size_t)N * HDIM * sizeof(float));
    (void)ws_size;

    const int* e_src = ei;
    const int* e_dst = ei + E;

    hipMemsetAsync(deg, 0, (size_t)2 * N * sizeof(int), stream);

    count_kernel<<<(E + 255) / 256, 256, 0, stream>>>(e_dst, deg, E);
    scan_kernel<<<1, 1024, 0, stream>>>(deg, rowptr, dinv, N);
    fill_kernel<<<(E + 255) / 256, 256, 0, stream>>>(e_src, e_dst, rowptr, fill, csr, E);

    lift_kernel<<<((size_t)N * HDIM + 255) / 256, 256, 0, stream>>>(x, Wx, bx, Wy, by, Xa, Ya, N);

    const float* Xc = Xa; const float* Yc = Ya;
    float* Xn = Xb; float* Yn = Yb;
    for (int l = 0; l < NLAYER; l++) {
        layer_kernel<<<(N + 3) / 4, 256, 0, stream>>>(
            Xc, Yc, Xn, Yn, rowptr, csr, dinv,
            alpha + l * HDIM, beta + l * HDIM, gamma + l * HDIM, delta + l * HDIM, N);
        const float* tX = Xc; const float* tY = Yc;
        Xc = Xn; Yc = Yn;
        Xn = (float*)tX; Yn = (float*)tY;
    }

    readout_kernel<<<(N + RO_NODES - 1) / RO_NODES, 256, 0, stream>>>(
        Xc, Yc, Wr, br, (float*)d_out, N);
}

// Round 2
// 832.952 us; speedup vs baseline: 1.2852x; 1.2852x over previous
//
#include <hip/hip_runtime.h>
#include <hip/hip_bf16.h>

// PPGNN: lift -> 5x (mean-aggregate + Lotka-Volterra Euler step) -> readout
// N=50000, E=800000, C_IN=128, H=96, C_OUT=40, L=5, DT=0.05
//
// Layout choice: node state stored interleaved as float2 pairs (Xc, Yc),
// 96 float2 per node. Gathers are coalesced dwordx2; each lane holds both
// aggX[c] and aggY[c] for its channel -> LV update is lane-local.

#define HDIM 96
#define CIN 128
#define COUT 40
#define NLAYER 5
#define DTC 0.05f

// ---------------- CSR build ----------------

__global__ void count_kernel(const int* __restrict__ dst, int* __restrict__ deg, int E) {
    int e = blockIdx.x * blockDim.x + threadIdx.x;
    if (e < E) atomicAdd(&deg[dst[e]], 1);
}

__global__ void scan_kernel(const int* __restrict__ deg, int* __restrict__ rowptr,
                            float* __restrict__ deg_inv, int N) {
    __shared__ int sdata[1024];
    __shared__ int s_carry;
    if (threadIdx.x == 0) s_carry = 0;
    __syncthreads();
    for (int base = 0; base < N; base += 1024) {
        int i = base + (int)threadIdx.x;
        int v = (i < N) ? deg[i] : 0;
        sdata[threadIdx.x] = v;
        __syncthreads();
        for (int off = 1; off < 1024; off <<= 1) {
            int t = (threadIdx.x >= (unsigned)off) ? sdata[threadIdx.x - off] : 0;
            __syncthreads();
            sdata[threadIdx.x] += t;
            __syncthreads();
        }
        if (i < N) {
            rowptr[i] = s_carry + sdata[threadIdx.x] - v;  // exclusive
            deg_inv[i] = 1.0f / fmaxf((float)v, 1.0f);
        }
        __syncthreads();
        if (threadIdx.x == 0) s_carry += sdata[1023];
        __syncthreads();
    }
    if (threadIdx.x == 0) rowptr[N] = s_carry;
}

__global__ void fill_kernel(const int* __restrict__ src, const int* __restrict__ dst,
                            const int* __restrict__ rowptr, int* __restrict__ fill,
                            int* __restrict__ csr, int E) {
    int e = blockIdx.x * blockDim.x + threadIdx.x;
    if (e < E) {
        int d = dst[e];
        int pos = rowptr[d] + atomicAdd(&fill[d], 1);
        csr[pos] = src[e];
    }
}

// ---------------- Lift: X=tanh(xWx+bx), Y=tanh(xWy+by) ----------------
// Block = 192 threads (3 waves) handles 16 nodes. x rows staged in LDS
// (pad +1 so the 4 node-slots hit distinct banks). Each thread computes
// 4 nodes x 2 channels (h, h+48) x {X,Y} = 16 accumulators.

#define LIFT_NODES 16

__global__ __launch_bounds__(192) void lift_kernel(
    const float* __restrict__ x,
    const float* __restrict__ Wx, const float* __restrict__ bx,
    const float* __restrict__ Wy, const float* __restrict__ by,
    float2* __restrict__ XY, int N) {
    __shared__ float sx[LIFT_NODES][CIN + 1];
    int t = threadIdx.x;
    int nbase = blockIdx.x * LIFT_NODES;
    int maxn = N - nbase;  // may exceed LIFT_NODES; clamp in loop

    // stage 16 x rows (2048 floats) as float4
    {
        const int row4 = CIN / 4;  // 32
        for (int i = t; i < LIFT_NODES * row4; i += blockDim.x) {
            int nl = i / row4;
            int c4 = i - nl * row4;
            float4 v = make_float4(0.f, 0.f, 0.f, 0.f);
            if (nl < maxn)
                v = ((const float4*)x)[(size_t)(nbase + nl) * row4 + c4];
            sx[nl][c4 * 4 + 0] = v.x;
            sx[nl][c4 * 4 + 1] = v.y;
            sx[nl][c4 * 4 + 2] = v.z;
            sx[nl][c4 * 4 + 3] = v.w;
        }
    }
    __syncthreads();

    int h = t % 48;
    int slot = t / 48;  // 0..3, each handles 4 local nodes
    int h1 = h + 48;

    float accx0[4], accx1[4], accy0[4], accy1[4];
    float bx0 = bx[h], bx1 = bx[h1], by0 = by[h], by1 = by[h1];
#pragma unroll
    for (int k = 0; k < 4; k++) {
        accx0[k] = bx0; accx1[k] = bx1;
        accy0[k] = by0; accy1[k] = by1;
    }

    for (int c = 0; c < CIN; c++) {
        float wx0 = Wx[c * HDIM + h], wx1 = Wx[c * HDIM + h1];
        float wy0 = Wy[c * HDIM + h], wy1 = Wy[c * HDIM + h1];
#pragma unroll
        for (int k = 0; k < 4; k++) {
            float xv = sx[slot * 4 + k][c];
            accx0[k] = fmaf(xv, wx0, accx0[k]);
            accx1[k] = fmaf(xv, wx1, accx1[k]);
            accy0[k] = fmaf(xv, wy0, accy0[k]);
            accy1[k] = fmaf(xv, wy1, accy1[k]);
        }
    }

#pragma unroll
    for (int k = 0; k < 4; k++) {
        int nl = slot * 4 + k;
        int nd = nbase + nl;
        if (nl < maxn) {
            XY[(size_t)nd * HDIM + h]  = make_float2(tanhf(accx0[k]), tanhf(accy0[k]));
            XY[(size_t)nd * HDIM + h1] = make_float2(tanhf(accx1[k]), tanhf(accy1[k]));
        }
    }
}

// ---------------- Layer: mean agg + LV Euler update ----------------
// One wave per node. CSR indices preloaded 64-at-a-time with one coalesced
// load, broadcast via __shfl (no per-edge index load latency). 4-edge unroll
// gives 8 independent row gathers in flight. Lane covers pair-channel `lane`
// and (lanes 0-31) pair-channel 64+lane.

#define LWPB 4

__global__ __launch_bounds__(256) void layer_kernel(
    const float2* __restrict__ XY, float2* __restrict__ XYn,
    const int* __restrict__ rowptr, const int* __restrict__ csr,
    const float* __restrict__ deg_inv,
    const float* __restrict__ alpha, const float* __restrict__ beta,
    const float* __restrict__ gamma, const float* __restrict__ delta,
    int N) {
    int wave = threadIdx.x >> 6;
    int lane = threadIdx.x & 63;
    int node = blockIdx.x * LWPB + wave;
    if (node >= N) return;

    int beg = rowptr[node];
    int cnt = rowptr[node + 1] - beg;

    bool lo = (lane < 32);
    int lane1 = 64 + lane;

    float ax0 = 0.f, ay0 = 0.f, ax1 = 0.f, ay1 = 0.f;

    for (int base = 0; base < cnt; base += 64) {
        int m = min(64, cnt - base);
        int sidx = (lane < m) ? csr[beg + base + lane] : 0;
        int j = 0;
        for (; j + 4 <= m; j += 4) {
            int s0 = __shfl(sidx, j);
            int s1 = __shfl(sidx, j + 1);
            int s2 = __shfl(sidx, j + 2);
            int s3 = __shfl(sidx, j + 3);
            const float2* r0 = XY + (size_t)s0 * HDIM;
            const float2* r1 = XY + (size_t)s1 * HDIM;
            const float2* r2 = XY + (size_t)s2 * HDIM;
            const float2* r3 = XY + (size_t)s3 * HDIM;
            float2 p0 = r0[lane];
            float2 p1 = r1[lane];
            float2 p2 = r2[lane];
            float2 p3 = r3[lane];
            ax0 += (p0.x + p1.x) + (p2.x + p3.x);
            ay0 += (p0.y + p1.y) + (p2.y + p3.y);
            if (lo) {
                float2 q0 = r0[lane1];
                float2 q1 = r1[lane1];
                float2 q2 = r2[lane1];
                float2 q3 = r3[lane1];
                ax1 += (q0.x + q1.x) + (q2.x + q3.x);
                ay1 += (q0.y + q1.y) + (q2.y + q3.y);
            }
        }
        for (; j < m; j++) {
            int s = __shfl(sidx, j);
            const float2* r = XY + (size_t)s * HDIM;
            float2 p = r[lane];
            ax0 += p.x;
            ay0 += p.y;
            if (lo) {
                float2 q = r[lane1];
                ax1 += q.x;
                ay1 += q.y;
            }
        }
    }

    float dinv = deg_inv[node];
    ax0 *= dinv; ay0 *= dinv; ax1 *= dinv; ay1 *= dinv;

    const float2* row = XY + (size_t)node * HDIM;
    float2* rown = XYn + (size_t)node * HDIM;
    {
        int c = lane;
        float2 v = row[c];
        float2 o;
        o.x = v.x + DTC * v.x * (alpha[c] - beta[c] * ay0);
        o.y = v.y + DTC * v.y * (-gamma[c] + delta[c] * ax0);
        rown[c] = o;
    }
    if (lo) {
        int c = lane1;
        float2 v = row[c];
        float2 o;
        o.x = v.x + DTC * v.x * (alpha[c] - beta[c] * ay1);
        o.y = v.y + DTC * v.y * (-gamma[c] + delta[c] * ax1);
        rown[c] = o;
    }
}

// ---------------- Readout: out = [X,Y] @ Wr + br ----------------
// Block = 256 threads; 6 nodes/block (240 active lanes in the dot phase).
// XY is interleaved; concat index h<96 -> v.x of pair h, h>=96 -> v.y.

#define RO_NODES 6

__global__ void readout_kernel(const float2* __restrict__ XY,
                               const float* __restrict__ Wr, const float* __restrict__ br,
                               float* __restrict__ out, int N) {
    __shared__ float sW[2 * HDIM * COUT];  // 192*40 = 7680 floats (30 KB)
    __shared__ float sB[COUT];
    __shared__ float2 sXY[RO_NODES * HDIM];  // 6*96 float2

    for (int i = threadIdx.x; i < 2 * HDIM * COUT; i += blockDim.x) sW[i] = Wr[i];
    if (threadIdx.x < COUT) sB[threadIdx.x] = br[threadIdx.x];

    int base_node = blockIdx.x * RO_NODES;
    for (int i = threadIdx.x; i < RO_NODES * HDIM; i += blockDim.x) {
        int li = i / HDIM;
        int p = i - li * HDIM;
        int nd = base_node + li;
        sXY[i] = (nd < N) ? XY[(size_t)nd * HDIM + p] : make_float2(0.f, 0.f);
    }
    __syncthreads();

    int t = threadIdx.x;
    int li = t / COUT;
    int o = t - li * COUT;
    int node = base_node + li;
    if (li < RO_NODES && node < N) {
        const float2* row = &sXY[li * HDIM];
        float acc = sB[o];
#pragma unroll
        for (int c = 0; c < HDIM; c++) {
            float2 v = row[c];
            acc = fmaf(v.x, sW[c * COUT + o], acc);             // X part (concat idx c)
            acc = fmaf(v.y, sW[(HDIM + c) * COUT + o], acc);    // Y part (concat idx 96+c)
        }
        out[(size_t)node * COUT + o] = acc;
    }
}

// ---------------- launch ----------------

extern "C" void kernel_launch(void* const* d_in, const int* in_sizes, int n_in,
                              void* d_out, int out_size, void* d_ws, size_t ws_size,
                              hipStream_t stream) {
    const float* x     = (const float*)d_in[0];
    const int*   ei    = (const int*)d_in[1];
    const float* Wx    = (const float*)d_in[2];
    const float* bx    = (const float*)d_in[3];
    const float* Wy    = (const float*)d_in[4];
    const float* by    = (const float*)d_in[5];
    const float* alpha = (const float*)d_in[6];
    const float* beta  = (const float*)d_in[7];
    const float* gamma = (const float*)d_in[8];
    const float* delta = (const float*)d_in[9];
    const float* Wr    = (const float*)d_in[10];
    const float* br    = (const float*)d_in[11];

    const int N = in_sizes[0] / CIN;
    const int E = in_sizes[1] / 2;

    // workspace carve-up (256B aligned)
    char* ws = (char*)d_ws;
    size_t off = 0;
    auto alloc = [&](size_t bytes) -> void* {
        off = (off + 255) & ~(size_t)255;
        void* p = ws + off;
        off += bytes;
        return p;
    };
    int* deg      = (int*)alloc((size_t)2 * N * sizeof(int));  // deg + fill, contiguous
    int* fill     = deg + N;
    int* rowptr   = (int*)alloc((size_t)(N + 1) * sizeof(int));
    int* csr      = (int*)alloc((size_t)E * sizeof(int));
    float* dinv   = (float*)alloc((size_t)N * sizeof(float));
    float2* XYa   = (float2*)alloc((size_t)N * HDIM * sizeof(float2));
    float2* XYb   = (float2*)alloc((size_t)N * HDIM * sizeof(float2));
    (void)ws_size;

    const int* e_src = ei;
    const int* e_dst = ei + E;

    hipMemsetAsync(deg, 0, (size_t)2 * N * sizeof(int), stream);

    count_kernel<<<(E + 255) / 256, 256, 0, stream>>>(e_dst, deg, E);
    scan_kernel<<<1, 1024, 0, stream>>>(deg, rowptr, dinv, N);
    fill_kernel<<<(E + 255) / 256, 256, 0, stream>>>(e_src, e_dst, rowptr, fill, csr, E);

    lift_kernel<<<(N + LIFT_NODES - 1) / LIFT_NODES, 192, 0, stream>>>(
        x, Wx, bx, Wy, by, XYa, N);

    const float2* XYc = XYa;
    float2* XYn = XYb;
    for (int l = 0; l < NLAYER; l++) {
        layer_kernel<<<(N + LWPB - 1) / LWPB, LWPB * 64, 0, stream>>>(
            XYc, XYn, rowptr, csr, dinv,
            alpha + l * HDIM, beta + l * HDIM, gamma + l * HDIM, delta + l * HDIM, N);
        const float2* t2 = XYc;
        XYc = XYn;
        XYn = (float2*)t2;
    }

    readout_kernel<<<(N + RO_NODES - 1) / RO_NODES, 256, 0, stream>>>(
        XYc, Wr, br, (float*)d_out, N);
}

// Round 3
// 757.889 us; speedup vs baseline: 1.4125x; 1.0990x over previous
//
#include <hip/hip_runtime.h>
#include <hip/hip_bf16.h>

// PPGNN: lift -> 5x (mean-aggregate + Lotka-Volterra Euler step) -> readout
// N=50000, E=800000, C_IN=128, H=96, C_OUT=40, L=5, DT=0.05
//
// Node state stored interleaved: row = 48 float4, float4 #l = (X[2l], Y[2l],
// X[2l+1], Y[2l+1]). One dwordx4 per lane (48 active lanes) fetches a full
// 768 B row per instruction; LV update is lane-local.

#define HDIM 96
#define CIN 128
#define COUT 40
#define NLAYER 5
#define DTC 0.05f

// ---------------- CSR build ----------------

__global__ void count_kernel(const int* __restrict__ dst, int* __restrict__ deg, int E) {
    int e = blockIdx.x * blockDim.x + threadIdx.x;
    if (e < E) atomicAdd(&deg[dst[e]], 1);
}

// Hierarchical scan of deg -> rowptr (exclusive), 1024 elems per block.
#define SCAN_ELEMS 1024

__global__ void scan_reduce_kernel(const int* __restrict__ deg, int* __restrict__ partials, int N) {
    __shared__ int sd[256];
    int t = threadIdx.x;
    int base = blockIdx.x * SCAN_ELEMS + t * 4;
    int s = 0;
#pragma unroll
    for (int k = 0; k < 4; k++) {
        int i = base + k;
        if (i < N) s += deg[i];
    }
    sd[t] = s;
    __syncthreads();
    for (int off = 128; off > 0; off >>= 1) {
        if (t < off) sd[t] += sd[t + off];
        __syncthreads();
    }
    if (t == 0) partials[blockIdx.x] = sd[0];
}

__global__ void scan_partials_kernel(const int* __restrict__ partials, int* __restrict__ offsets,
                                     int* __restrict__ rowptr, int nblocks, int N) {
    __shared__ int sd[1024];
    int t = threadIdx.x;
    int v = (t < nblocks) ? partials[t] : 0;
    sd[t] = v;
    __syncthreads();
    for (int off = 1; off < 1024; off <<= 1) {
        int tv = (t >= off) ? sd[t - off] : 0;
        __syncthreads();
        sd[t] += tv;
        __syncthreads();
    }
    if (t < nblocks) offsets[t] = sd[t] - v;  // exclusive
    if (t == 1023) rowptr[N] = sd[1023];      // total = E
}

__global__ void scan_local_kernel(const int* __restrict__ deg, const int* __restrict__ offsets,
                                  int* __restrict__ rowptr, float* __restrict__ deg_inv, int N) {
    __shared__ int ssum[256];
    int t = threadIdx.x;
    int base = blockIdx.x * SCAN_ELEMS + t * 4;
    int v[4];
    int s = 0;
#pragma unroll
    for (int k = 0; k < 4; k++) {
        int i = base + k;
        v[k] = (i < N) ? deg[i] : 0;
        s += v[k];
    }
    ssum[t] = s;
    __syncthreads();
    for (int off = 1; off < 256; off <<= 1) {
        int tv = (t >= off) ? ssum[t - off] : 0;
        __syncthreads();
        ssum[t] += tv;
        __syncthreads();
    }
    int excl = ssum[t] - s + offsets[blockIdx.x];
#pragma unroll
    for (int k = 0; k < 4; k++) {
        int i = base + k;
        if (i < N) {
            rowptr[i] = excl;
            deg_inv[i] = 1.0f / fmaxf((float)v[k], 1.0f);
            excl += v[k];
        }
    }
}

__global__ void fill_kernel(const int* __restrict__ src, const int* __restrict__ dst,
                            const int* __restrict__ rowptr, int* __restrict__ fill,
                            int* __restrict__ csr, int E) {
    int e = blockIdx.x * blockDim.x + threadIdx.x;
    if (e < E) {
        int d = dst[e];
        int pos = rowptr[d] + atomicAdd(&fill[d], 1);
        csr[pos] = src[e];
    }
}

// ---------------- Lift: X=tanh(xWx+bx), Y=tanh(xWy+by) ----------------
// Block = 192 threads handles 16 nodes; x rows staged in LDS. Each thread
// computes 4 nodes x channels {h, h+48} x {X,Y} = 16 accumulators.
// Output written in interleaved float4 layout: XY4[node*48 + c] where
// element c covers channels 2c (x,y) and 2c+1 (z,w). Thread with h writes
// channel h of X/Y -> scatter via per-channel float2 stores (pair index h).

#define LIFT_NODES 16

__global__ __launch_bounds__(192) void lift_kernel(
    const float* __restrict__ x,
    const float* __restrict__ Wx, const float* __restrict__ bx,
    const float* __restrict__ Wy, const float* __restrict__ by,
    float2* __restrict__ XY, int N) {
    __shared__ float sx[LIFT_NODES][CIN + 1];
    int t = threadIdx.x;
    int nbase = blockIdx.x * LIFT_NODES;
    int maxn = N - nbase;

    {
        const int row4 = CIN / 4;  // 32
        for (int i = t; i < LIFT_NODES * row4; i += blockDim.x) {
            int nl = i / row4;
            int c4 = i - nl * row4;
            float4 v = make_float4(0.f, 0.f, 0.f, 0.f);
            if (nl < maxn)
                v = ((const float4*)x)[(size_t)(nbase + nl) * row4 + c4];
            sx[nl][c4 * 4 + 0] = v.x;
            sx[nl][c4 * 4 + 1] = v.y;
            sx[nl][c4 * 4 + 2] = v.z;
            sx[nl][c4 * 4 + 3] = v.w;
        }
    }
    __syncthreads();

    int h = t % 48;
    int slot = t / 48;
    int h1 = h + 48;

    float accx0[4], accx1[4], accy0[4], accy1[4];
    float bx0 = bx[h], bx1 = bx[h1], by0 = by[h], by1 = by[h1];
#pragma unroll
    for (int k = 0; k < 4; k++) {
        accx0[k] = bx0; accx1[k] = bx1;
        accy0[k] = by0; accy1[k] = by1;
    }

    for (int c = 0; c < CIN; c++) {
        float wx0 = Wx[c * HDIM + h], wx1 = Wx[c * HDIM + h1];
        float wy0 = Wy[c * HDIM + h], wy1 = Wy[c * HDIM + h1];
#pragma unroll
        for (int k = 0; k < 4; k++) {
            float xv = sx[slot * 4 + k][c];
            accx0[k] = fmaf(xv, wx0, accx0[k]);
            accx1[k] = fmaf(xv, wx1, accx1[k]);
            accy0[k] = fmaf(xv, wy0, accy0[k]);
            accy1[k] = fmaf(xv, wy1, accy1[k]);
        }
    }

#pragma unroll
    for (int k = 0; k < 4; k++) {
        int nl = slot * 4 + k;
        int nd = nbase + nl;
        if (nl < maxn) {
            XY[(size_t)nd * HDIM + h]  = make_float2(tanhf(accx0[k]), tanhf(accy0[k]));
            XY[(size_t)nd * HDIM + h1] = make_float2(tanhf(accx1[k]), tanhf(accy1[k]));
        }
    }
}

// ---------------- Layer: mean agg + LV Euler update ----------------
// One wave per node. CSR indices preloaded 64-wide, broadcast via __shfl.
// Lanes 0-47 each load one float4 (2 channel pairs) per gathered row:
// one dwordx4 instruction per row, 8-edge unroll for MLP.

#define LWPB 4

__global__ __launch_bounds__(256) void layer_kernel(
    const float4* __restrict__ XY4, float4* __restrict__ XYn4,
    const int* __restrict__ rowptr, const int* __restrict__ csr,
    const float* __restrict__ deg_inv,
    const float* __restrict__ alpha, const float* __restrict__ beta,
    const float* __restrict__ gamma, const float* __restrict__ delta,
    int N) {
    int wave = threadIdx.x >> 6;
    int lane = threadIdx.x & 63;
    int node = blockIdx.x * LWPB + wave;
    if (node >= N) return;

    int beg = rowptr[node];
    int cnt = rowptr[node + 1] - beg;
    bool act = (lane < 48);

    // acc: channels 2*lane (x,y) and 2*lane+1 (z,w); a=aggX, b=aggY
    float ax0 = 0.f, ay0 = 0.f, ax1 = 0.f, ay1 = 0.f;

    for (int base = 0; base < cnt; base += 64) {
        int m = min(64, cnt - base);
        int sidx = (lane < m) ? csr[beg + base + lane] : 0;
        int j = 0;
        for (; j + 8 <= m; j += 8) {
            int s0 = __shfl(sidx, j);
            int s1 = __shfl(sidx, j + 1);
            int s2 = __shfl(sidx, j + 2);
            int s3 = __shfl(sidx, j + 3);
            int s4 = __shfl(sidx, j + 4);
            int s5 = __shfl(sidx, j + 5);
            int s6 = __shfl(sidx, j + 6);
            int s7 = __shfl(sidx, j + 7);
            if (act) {
                float4 v0 = XY4[(size_t)s0 * 48 + lane];
                float4 v1 = XY4[(size_t)s1 * 48 + lane];
                float4 v2 = XY4[(size_t)s2 * 48 + lane];
                float4 v3 = XY4[(size_t)s3 * 48 + lane];
                float4 v4 = XY4[(size_t)s4 * 48 + lane];
                float4 v5 = XY4[(size_t)s5 * 48 + lane];
                float4 v6 = XY4[(size_t)s6 * 48 + lane];
                float4 v7 = XY4[(size_t)s7 * 48 + lane];
                ax0 += ((v0.x + v1.x) + (v2.x + v3.x)) + ((v4.x + v5.x) + (v6.x + v7.x));
                ay0 += ((v0.y + v1.y) + (v2.y + v3.y)) + ((v4.y + v5.y) + (v6.y + v7.y));
                ax1 += ((v0.z + v1.z) + (v2.z + v3.z)) + ((v4.z + v5.z) + (v6.z + v7.z));
                ay1 += ((v0.w + v1.w) + (v2.w + v3.w)) + ((v4.w + v5.w) + (v6.w + v7.w));
            }
        }
        for (; j < m; j++) {
            int s = __shfl(sidx, j);
            if (act) {
                float4 v = XY4[(size_t)s * 48 + lane];
                ax0 += v.x; ay0 += v.y; ax1 += v.z; ay1 += v.w;
            }
        }
    }

    float dinv = deg_inv[node];
    if (act) {
        ax0 *= dinv; ay0 *= dinv; ax1 *= dinv; ay1 *= dinv;
        float2 a2 = ((const float2*)alpha)[lane];
        float2 b2 = ((const float2*)beta)[lane];
        float2 g2 = ((const float2*)gamma)[lane];
        float2 d2 = ((const float2*)delta)[lane];
        float4 v = XY4[(size_t)node * 48 + lane];
        float4 o;
        o.x = v.x + DTC * v.x * (a2.x - b2.x * ay0);
        o.y = v.y + DTC * v.y * (-g2.x + d2.x * ax0);
        o.z = v.z + DTC * v.z * (a2.y - b2.y * ay1);
        o.w = v.w + DTC * v.w * (-g2.y + d2.y * ax1);
        XYn4[(size_t)node * 48 + lane] = o;
    }
}

// ---------------- Readout: out = [X,Y] @ Wr + br ----------------

#define RO_NODES 6

__global__ void readout_kernel(const float2* __restrict__ XY,
                               const float* __restrict__ Wr, const float* __restrict__ br,
                               float* __restrict__ out, int N) {
    __shared__ float sW[2 * HDIM * COUT];  // 7680 floats (30 KB)
    __shared__ float sB[COUT];
    __shared__ float2 sXY[RO_NODES * HDIM];

    for (int i = threadIdx.x; i < 2 * HDIM * COUT; i += blockDim.x) sW[i] = Wr[i];
    if (threadIdx.x < COUT) sB[threadIdx.x] = br[threadIdx.x];

    int base_node = blockIdx.x * RO_NODES;
    for (int i = threadIdx.x; i < RO_NODES * HDIM; i += blockDim.x) {
        int li = i / HDIM;
        int p = i - li * HDIM;
        int nd = base_node + li;
        sXY[i] = (nd < N) ? XY[(size_t)nd * HDIM + p] : make_float2(0.f, 0.f);
    }
    __syncthreads();

    int t = threadIdx.x;
    int li = t / COUT;
    int o = t - li * COUT;
    int node = base_node + li;
    if (li < RO_NODES && node < N) {
        const float2* row = &sXY[li * HDIM];
        float acc = sB[o];
#pragma unroll
        for (int c = 0; c < HDIM; c++) {
            float2 v = row[c];
            acc = fmaf(v.x, sW[c * COUT + o], acc);
            acc = fmaf(v.y, sW[(HDIM + c) * COUT + o], acc);
        }
        out[(size_t)node * COUT + o] = acc;
    }
}

// ---------------- launch ----------------

extern "C" void kernel_launch(void* const* d_in, const int* in_sizes, int n_in,
                              void* d_out, int out_size, void* d_ws, size_t ws_size,
                              hipStream_t stream) {
    const float* x     = (const float*)d_in[0];
    const int*   ei    = (const int*)d_in[1];
    const float* Wx    = (const float*)d_in[2];
    const float* bx    = (const float*)d_in[3];
    const float* Wy    = (const float*)d_in[4];
    const float* by    = (const float*)d_in[5];
    const float* alpha = (const float*)d_in[6];
    const float* beta  = (const float*)d_in[7];
    const float* gamma = (const float*)d_in[8];
    const float* delta = (const float*)d_in[9];
    const float* Wr    = (const float*)d_in[10];
    const float* br    = (const float*)d_in[11];

    const int N = in_sizes[0] / CIN;
    const int E = in_sizes[1] / 2;
    const int nscan = (N + SCAN_ELEMS - 1) / SCAN_ELEMS;  // 49 for N=50000

    char* ws = (char*)d_ws;
    size_t off = 0;
    auto alloc = [&](size_t bytes) -> void* {
        off = (off + 255) & ~(size_t)255;
        void* p = ws + off;
        off += bytes;
        return p;
    };
    int* deg      = (int*)alloc((size_t)2 * N * sizeof(int));  // deg + fill
    int* fill     = deg + N;
    int* rowptr   = (int*)alloc((size_t)(N + 1) * sizeof(int));
    int* csr      = (int*)alloc((size_t)E * sizeof(int));
    float* dinv   = (float*)alloc((size_t)N * sizeof(float));
    int* partials = (int*)alloc((size_t)nscan * sizeof(int));
    int* offsets  = (int*)alloc((size_t)nscan * sizeof(int));
    float2* XYa   = (float2*)alloc((size_t)N * HDIM * sizeof(float2));
    float2* XYb   = (float2*)alloc((size_t)N * HDIM * sizeof(float2));
    (void)ws_size;

    const int* e_src = ei;
    const int* e_dst = ei + E;

    hipMemsetAsync(deg, 0, (size_t)2 * N * sizeof(int), stream);

    count_kernel<<<(E + 255) / 256, 256, 0, stream>>>(e_dst, deg, E);
    scan_reduce_kernel<<<nscan, 256, 0, stream>>>(deg, partials, N);
    scan_partials_kernel<<<1, 1024, 0, stream>>>(partials, offsets, rowptr, nscan, N);
    scan_local_kernel<<<nscan, 256, 0, stream>>>(deg, offsets, rowptr, dinv, N);
    fill_kernel<<<(E + 255) / 256, 256, 0, stream>>>(e_src, e_dst, rowptr, fill, csr, E);

    lift_kernel<<<(N + LIFT_NODES - 1) / LIFT_NODES, 192, 0, stream>>>(
        x, Wx, bx, Wy, by, XYa, N);

    const float2* XYc = XYa;
    float2* XYn = XYb;
    for (int l = 0; l < NLAYER; l++) {
        layer_kernel<<<(N + LWPB - 1) / LWPB, LWPB * 64, 0, stream>>>(
            (const float4*)XYc, (float4*)XYn, rowptr, csr, dinv,
            alpha + l * HDIM, beta + l * HDIM, gamma + l * HDIM, delta + l * HDIM, N);
        const float2* t2 = XYc;
        XYc = XYn;
        XYn = (float2*)t2;
    }

    readout_kernel<<<(N + RO_NODES - 1) / RO_NODES, 256, 0, stream>>>(
        XYc, Wr, br, (float*)d_out, N);
}

// Round 4
// 565.583 us; speedup vs baseline: 1.8928x; 1.3400x over previous
//
#include <hip/hip_runtime.h>
#include <hip/hip_bf16.h>

// PPGNN: lift -> 5x (mean-aggregate + Lotka-Volterra Euler step) -> readout
// N=50000, E=800000, C_IN=128, H=96, C_OUT=40, L=5, DT=0.05
//
// Layer kernels are L3-bandwidth-bound on the neighbor-row gathers
// (614 MB/layer fp32). Fix: fp32 master state + packed bf16 mirror
// (uint = bf16 X | bf16 Y << 16, row = 96 uints = 384 B). Gathers read the
// mirror (half the bytes); the Euler update runs in fp32 and emits the
// next mirror. Mirror error enters only via the aggregated mean scaled by
// DT*X*beta ~ 0.005 -> ~1e-5/layer, negligible vs 6e-2 threshold.

#define HDIM 96
#define CIN 128
#define COUT 40
#define NLAYER 5
#define DTC 0.05f

__device__ __forceinline__ unsigned pack_bf16_pair(float xf, float yf) {
    unsigned ux = __float_as_uint(xf);
    unsigned uy = __float_as_uint(yf);
    ux = (ux + 0x7fffu + ((ux >> 16) & 1u)) >> 16;   // RNE to bf16
    uy = (uy + 0x7fffu + ((uy >> 16) & 1u)) >> 16;
    return ux | (uy << 16);
}

// ---------------- CSR build ----------------

__global__ void count_kernel(const int* __restrict__ dst, int* __restrict__ deg, int E) {
    int e = blockIdx.x * blockDim.x + threadIdx.x;
    if (e < E) atomicAdd(&deg[dst[e]], 1);
}

#define SCAN_ELEMS 1024

__global__ void scan_reduce_kernel(const int* __restrict__ deg, int* __restrict__ partials, int N) {
    __shared__ int sd[256];
    int t = threadIdx.x;
    int base = blockIdx.x * SCAN_ELEMS + t * 4;
    int s = 0;
#pragma unroll
    for (int k = 0; k < 4; k++) {
        int i = base + k;
        if (i < N) s += deg[i];
    }
    sd[t] = s;
    __syncthreads();
    for (int off = 128; off > 0; off >>= 1) {
        if (t < off) sd[t] += sd[t + off];
        __syncthreads();
    }
    if (t == 0) partials[blockIdx.x] = sd[0];
}

__global__ void scan_partials_kernel(const int* __restrict__ partials, int* __restrict__ offsets,
                                     int* __restrict__ rowptr, int nblocks, int N) {
    __shared__ int sd[1024];
    int t = threadIdx.x;
    int v = (t < nblocks) ? partials[t] : 0;
    sd[t] = v;
    __syncthreads();
    for (int off = 1; off < 1024; off <<= 1) {
        int tv = (t >= off) ? sd[t - off] : 0;
        __syncthreads();
        sd[t] += tv;
        __syncthreads();
    }
    if (t < nblocks) offsets[t] = sd[t] - v;  // exclusive
    if (t == 1023) rowptr[N] = sd[1023];      // total = E
}

__global__ void scan_local_kernel(const int* __restrict__ deg, const int* __restrict__ offsets,
                                  int* __restrict__ rowptr, float* __restrict__ deg_inv, int N) {
    __shared__ int ssum[256];
    int t = threadIdx.x;
    int base = blockIdx.x * SCAN_ELEMS + t * 4;
    int v[4];
    int s = 0;
#pragma unroll
    for (int k = 0; k < 4; k++) {
        int i = base + k;
        v[k] = (i < N) ? deg[i] : 0;
        s += v[k];
    }
    ssum[t] = s;
    __syncthreads();
    for (int off = 1; off < 256; off <<= 1) {
        int tv = (t >= off) ? ssum[t - off] : 0;
        __syncthreads();
        ssum[t] += tv;
        __syncthreads();
    }
    int excl = ssum[t] - s + offsets[blockIdx.x];
#pragma unroll
    for (int k = 0; k < 4; k++) {
        int i = base + k;
        if (i < N) {
            rowptr[i] = excl;
            deg_inv[i] = 1.0f / fmaxf((float)v[k], 1.0f);
            excl += v[k];
        }
    }
}

__global__ void fill_kernel(const int* __restrict__ src, const int* __restrict__ dst,
                            const int* __restrict__ rowptr, int* __restrict__ fill,
                            int* __restrict__ csr, int E) {
    int e = blockIdx.x * blockDim.x + threadIdx.x;
    if (e < E) {
        int d = dst[e];
        int pos = rowptr[d] + atomicAdd(&fill[d], 1);
        csr[pos] = src[e];
    }
}

// ---------------- Lift: X=tanh(xWx+bx), Y=tanh(xWy+by) ----------------
// Writes fp32 state (float2 pairs) + bf16 mirror (uint per channel).

#define LIFT_NODES 16

__global__ __launch_bounds__(192) void lift_kernel(
    const float* __restrict__ x,
    const float* __restrict__ Wx, const float* __restrict__ bx,
    const float* __restrict__ Wy, const float* __restrict__ by,
    float2* __restrict__ XY, unsigned* __restrict__ M, int N) {
    __shared__ float sx[LIFT_NODES][CIN + 1];
    int t = threadIdx.x;
    int nbase = blockIdx.x * LIFT_NODES;
    int maxn = N - nbase;

    {
        const int row4 = CIN / 4;  // 32
        for (int i = t; i < LIFT_NODES * row4; i += blockDim.x) {
            int nl = i / row4;
            int c4 = i - nl * row4;
            float4 v = make_float4(0.f, 0.f, 0.f, 0.f);
            if (nl < maxn)
                v = ((const float4*)x)[(size_t)(nbase + nl) * row4 + c4];
            sx[nl][c4 * 4 + 0] = v.x;
            sx[nl][c4 * 4 + 1] = v.y;
            sx[nl][c4 * 4 + 2] = v.z;
            sx[nl][c4 * 4 + 3] = v.w;
        }
    }
    __syncthreads();

    int h = t % 48;
    int slot = t / 48;
    int h1 = h + 48;

    float accx0[4], accx1[4], accy0[4], accy1[4];
    float bx0 = bx[h], bx1 = bx[h1], by0 = by[h], by1 = by[h1];
#pragma unroll
    for (int k = 0; k < 4; k++) {
        accx0[k] = bx0; accx1[k] = bx1;
        accy0[k] = by0; accy1[k] = by1;
    }

    for (int c = 0; c < CIN; c++) {
        float wx0 = Wx[c * HDIM + h], wx1 = Wx[c * HDIM + h1];
        float wy0 = Wy[c * HDIM + h], wy1 = Wy[c * HDIM + h1];
#pragma unroll
        for (int k = 0; k < 4; k++) {
            float xv = sx[slot * 4 + k][c];
            accx0[k] = fmaf(xv, wx0, accx0[k]);
            accx1[k] = fmaf(xv, wx1, accx1[k]);
            accy0[k] = fmaf(xv, wy0, accy0[k]);
            accy1[k] = fmaf(xv, wy1, accy1[k]);
        }
    }

#pragma unroll
    for (int k = 0; k < 4; k++) {
        int nl = slot * 4 + k;
        int nd = nbase + nl;
        if (nl < maxn) {
            float x0 = tanhf(accx0[k]), y0 = tanhf(accy0[k]);
            float x1 = tanhf(accx1[k]), y1 = tanhf(accy1[k]);
            XY[(size_t)nd * HDIM + h]  = make_float2(x0, y0);
            XY[(size_t)nd * HDIM + h1] = make_float2(x1, y1);
            M[(size_t)nd * HDIM + h]  = pack_bf16_pair(x0, y0);
            M[(size_t)nd * HDIM + h1] = pack_bf16_pair(x1, y1);
        }
    }
}

// ---------------- Layer: mean agg + LV Euler update ----------------
// One wave per node. CSR indices preloaded 64-wide, broadcast via __shfl.
// Gathers read the bf16 mirror: lanes 0-47 each load uint2 (channels
// 2l, 2l+1) -> one dwordx2 / 384 B per row. 8-edge unroll for MLP.
// Update reads the fp32 row, writes fp32 next + bf16 mirror next.

#define LWPB 4

__global__ __launch_bounds__(256) void layer_kernel(
    const unsigned* __restrict__ M, const float4* __restrict__ XY4,
    float4* __restrict__ XYn4, unsigned* __restrict__ Mn,
    const int* __restrict__ rowptr, const int* __restrict__ csr,
    const float* __restrict__ deg_inv,
    const float* __restrict__ alpha, const float* __restrict__ beta,
    const float* __restrict__ gamma, const float* __restrict__ delta,
    int N) {
    int wave = threadIdx.x >> 6;
    int lane = threadIdx.x & 63;
    int node = blockIdx.x * LWPB + wave;
    if (node >= N) return;

    int beg = rowptr[node];
    int cnt = rowptr[node + 1] - beg;
    bool act = (lane < 48);

    // acc: channels 2*lane (ax0/ay0) and 2*lane+1 (ax1/ay1)
    float ax0 = 0.f, ay0 = 0.f, ax1 = 0.f, ay1 = 0.f;

#define UNPACK_ACC(u)                                              \
    do {                                                           \
        ax0 += __uint_as_float((u).x << 16);                       \
        ay0 += __uint_as_float((u).x & 0xffff0000u);               \
        ax1 += __uint_as_float((u).y << 16);                       \
        ay1 += __uint_as_float((u).y & 0xffff0000u);               \
    } while (0)

    for (int base = 0; base < cnt; base += 64) {
        int m = min(64, cnt - base);
        int sidx = (lane < m) ? csr[beg + base + lane] : 0;
        int j = 0;
        for (; j + 8 <= m; j += 8) {
            int s0 = __shfl(sidx, j);
            int s1 = __shfl(sidx, j + 1);
            int s2 = __shfl(sidx, j + 2);
            int s3 = __shfl(sidx, j + 3);
            int s4 = __shfl(sidx, j + 4);
            int s5 = __shfl(sidx, j + 5);
            int s6 = __shfl(sidx, j + 6);
            int s7 = __shfl(sidx, j + 7);
            if (act) {
                uint2 u0 = ((const uint2*)(M + (size_t)s0 * HDIM))[lane];
                uint2 u1 = ((const uint2*)(M + (size_t)s1 * HDIM))[lane];
                uint2 u2 = ((const uint2*)(M + (size_t)s2 * HDIM))[lane];
                uint2 u3 = ((const uint2*)(M + (size_t)s3 * HDIM))[lane];
                uint2 u4 = ((const uint2*)(M + (size_t)s4 * HDIM))[lane];
                uint2 u5 = ((const uint2*)(M + (size_t)s5 * HDIM))[lane];
                uint2 u6 = ((const uint2*)(M + (size_t)s6 * HDIM))[lane];
                uint2 u7 = ((const uint2*)(M + (size_t)s7 * HDIM))[lane];
                UNPACK_ACC(u0); UNPACK_ACC(u1); UNPACK_ACC(u2); UNPACK_ACC(u3);
                UNPACK_ACC(u4); UNPACK_ACC(u5); UNPACK_ACC(u6); UNPACK_ACC(u7);
            }
        }
        for (; j < m; j++) {
            int s = __shfl(sidx, j);
            if (act) {
                uint2 u = ((const uint2*)(M + (size_t)s * HDIM))[lane];
                UNPACK_ACC(u);
            }
        }
    }
#undef UNPACK_ACC

    float dinv = deg_inv[node];
    if (act) {
        ax0 *= dinv; ay0 *= dinv; ax1 *= dinv; ay1 *= dinv;
        float2 a2 = ((const float2*)alpha)[lane];
        float2 b2 = ((const float2*)beta)[lane];
        float2 g2 = ((const float2*)gamma)[lane];
        float2 d2 = ((const float2*)delta)[lane];
        float4 v = XY4[(size_t)node * 48 + lane];
        float4 o;
        o.x = v.x + DTC * v.x * (a2.x - b2.x * ay0);
        o.y = v.y + DTC * v.y * (-g2.x + d2.x * ax0);
        o.z = v.z + DTC * v.z * (a2.y - b2.y * ay1);
        o.w = v.w + DTC * v.w * (-g2.y + d2.y * ax1);
        XYn4[(size_t)node * 48 + lane] = o;
        if (Mn)
            ((uint2*)(Mn + (size_t)node * HDIM))[lane] =
                make_uint2(pack_bf16_pair(o.x, o.y), pack_bf16_pair(o.z, o.w));
    }
}

// ---------------- Readout: out = [X,Y] @ Wr + br ----------------

#define RO_NODES 6

__global__ void readout_kernel(const float2* __restrict__ XY,
                               const float* __restrict__ Wr, const float* __restrict__ br,
                               float* __restrict__ out, int N) {
    __shared__ float sW[2 * HDIM * COUT];  // 7680 floats (30 KB)
    __shared__ float sB[COUT];
    __shared__ float2 sXY[RO_NODES * HDIM];

    for (int i = threadIdx.x; i < 2 * HDIM * COUT; i += blockDim.x) sW[i] = Wr[i];
    if (threadIdx.x < COUT) sB[threadIdx.x] = br[threadIdx.x];

    int base_node = blockIdx.x * RO_NODES;
    for (int i = threadIdx.x; i < RO_NODES * HDIM; i += blockDim.x) {
        int li = i / HDIM;
        int p = i - li * HDIM;
        int nd = base_node + li;
        sXY[i] = (nd < N) ? XY[(size_t)nd * HDIM + p] : make_float2(0.f, 0.f);
    }
    __syncthreads();

    int t = threadIdx.x;
    int li = t / COUT;
    int o = t - li * COUT;
    int node = base_node + li;
    if (li < RO_NODES && node < N) {
        const float2* row = &sXY[li * HDIM];
        float acc = sB[o];
#pragma unroll
        for (int c = 0; c < HDIM; c++) {
            float2 v = row[c];
            acc = fmaf(v.x, sW[c * COUT + o], acc);
            acc = fmaf(v.y, sW[(HDIM + c) * COUT + o], acc);
        }
        out[(size_t)node * COUT + o] = acc;
    }
}

// ---------------- launch ----------------

extern "C" void kernel_launch(void* const* d_in, const int* in_sizes, int n_in,
                              void* d_out, int out_size, void* d_ws, size_t ws_size,
                              hipStream_t stream) {
    const float* x     = (const float*)d_in[0];
    const int*   ei    = (const int*)d_in[1];
    const float* Wx    = (const float*)d_in[2];
    const float* bx    = (const float*)d_in[3];
    const float* Wy    = (const float*)d_in[4];
    const float* by    = (const float*)d_in[5];
    const float* alpha = (const float*)d_in[6];
    const float* beta  = (const float*)d_in[7];
    const float* gamma = (const float*)d_in[8];
    const float* delta = (const float*)d_in[9];
    const float* Wr    = (const float*)d_in[10];
    const float* br    = (const float*)d_in[11];

    const int N = in_sizes[0] / CIN;
    const int E = in_sizes[1] / 2;
    const int nscan = (N + SCAN_ELEMS - 1) / SCAN_ELEMS;  // 49 for N=50000

    char* ws = (char*)d_ws;
    size_t off = 0;
    auto alloc = [&](size_t bytes) -> void* {
        off = (off + 255) & ~(size_t)255;
        void* p = ws + off;
        off += bytes;
        return p;
    };
    int* deg       = (int*)alloc((size_t)2 * N * sizeof(int));  // deg + fill
    int* fill      = deg + N;
    int* rowptr    = (int*)alloc((size_t)(N + 1) * sizeof(int));
    int* csr       = (int*)alloc((size_t)E * sizeof(int));
    float* dinv    = (float*)alloc((size_t)N * sizeof(float));
    int* partials  = (int*)alloc((size_t)nscan * sizeof(int));
    int* offsets   = (int*)alloc((size_t)nscan * sizeof(int));
    float2* XYa    = (float2*)alloc((size_t)N * HDIM * sizeof(float2));
    float2* XYb    = (float2*)alloc((size_t)N * HDIM * sizeof(float2));
    unsigned* Ma   = (unsigned*)alloc((size_t)N * HDIM * sizeof(unsigned));
    unsigned* Mb   = (unsigned*)alloc((size_t)N * HDIM * sizeof(unsigned));
    (void)ws_size;

    const int* e_src = ei;
    const int* e_dst = ei + E;

    hipMemsetAsync(deg, 0, (size_t)2 * N * sizeof(int), stream);

    count_kernel<<<(E + 255) / 256, 256, 0, stream>>>(e_dst, deg, E);
    scan_reduce_kernel<<<nscan, 256, 0, stream>>>(deg, partials, N);
    scan_partials_kernel<<<1, 1024, 0, stream>>>(partials, offsets, rowptr, nscan, N);
    scan_local_kernel<<<nscan, 256, 0, stream>>>(deg, offsets, rowptr, dinv, N);
    fill_kernel<<<(E + 255) / 256, 256, 0, stream>>>(e_src, e_dst, rowptr, fill, csr, E);

    lift_kernel<<<(N + LIFT_NODES - 1) / LIFT_NODES, 192, 0, stream>>>(
        x, Wx, bx, Wy, by, XYa, Ma, N);

    const float2* XYc = XYa;
    float2* XYn = XYb;
    const unsigned* Mc = Ma;
    unsigned* Mnx = Mb;
    for (int l = 0; l < NLAYER; l++) {
        layer_kernel<<<(N + LWPB - 1) / LWPB, LWPB * 64, 0, stream>>>(
            Mc, (const float4*)XYc, (float4*)XYn,
            (l == NLAYER - 1) ? (unsigned*)nullptr : Mnx,
            rowptr, csr, dinv,
            alpha + l * HDIM, beta + l * HDIM, gamma + l * HDIM, delta + l * HDIM, N);
        const float2* t2 = XYc; XYc = XYn; XYn = (float2*)t2;
        const unsigned* tm = Mc; Mc = Mnx; Mnx = (unsigned*)tm;
    }

    readout_kernel<<<(N + RO_NODES - 1) / RO_NODES, 256, 0, stream>>>(
        XYc, Wr, br, (float*)d_out, N);
}

// Round 5
// 442.801 us; speedup vs baseline: 2.4177x; 1.2773x over previous
//
#include <hip/hip_runtime.h>
#include <hip/hip_bf16.h>

// PPGNN: lift -> 5x (mean-aggregate + Lotka-Volterra Euler step) -> readout
// N=50000, E=800000, C_IN=128, H=96, C_OUT=40, L=5, DT=0.05
//
// fp32 master state XY (float2/channel). Two derived mirrors:
//  - fp8 e4m3 mirror F (ushort/channel = X,Y fp8 pair; row = 192 B) -- what
//    the layer gathers read (L3-BW-bound path; error enters only via
//    DT*X*beta*(agg err) ~ 4e-5/layer).
//  - bf16 mirror Mb16 (uint/channel; row = 384 B) written by the LAST layer
//    only, consumed by the MFMA readout.
// Readout = [50000,192]x[192,40] GEMM on mfma_f32_16x16x32_bf16.

#define HDIM 96
#define CIN 128
#define COUT 40
#define NLAYER 5
#define DTC 0.05f

typedef float  vfloat2 __attribute__((ext_vector_type(2)));
typedef float  vfloat4 __attribute__((ext_vector_type(4)));
typedef short  vshort8 __attribute__((ext_vector_type(8)));

__device__ __forceinline__ unsigned pack_bf16_pair(float xf, float yf) {
    unsigned ux = __float_as_uint(xf);
    unsigned uy = __float_as_uint(yf);
    ux = (ux + 0x7fffu + ((ux >> 16) & 1u)) >> 16;   // RNE to bf16
    uy = (uy + 0x7fffu + ((uy >> 16) & 1u)) >> 16;
    return ux | (uy << 16);
}

__device__ __forceinline__ unsigned short pack_fp8_pair(float xf, float yf) {
    return (unsigned short)(__builtin_amdgcn_cvt_pk_fp8_f32(xf, yf, 0, false) & 0xffff);
}

__device__ __forceinline__ unsigned pack_fp8_quad(float x0, float y0, float x1, float y1) {
    int lo = __builtin_amdgcn_cvt_pk_fp8_f32(x0, y0, 0, false);
    int full = __builtin_amdgcn_cvt_pk_fp8_f32(x1, y1, lo, true);
    return (unsigned)full;
}

// ---------------- CSR build ----------------

__global__ void count_kernel(const int* __restrict__ dst, int* __restrict__ deg, int E) {
    int e = blockIdx.x * blockDim.x + threadIdx.x;
    if (e < E) atomicAdd(&deg[dst[e]], 1);
}

#define SCAN_ELEMS 1024

__global__ void scan_reduce_kernel(const int* __restrict__ deg, int* __restrict__ partials, int N) {
    __shared__ int sd[256];
    int t = threadIdx.x;
    int base = blockIdx.x * SCAN_ELEMS + t * 4;
    int s = 0;
#pragma unroll
    for (int k = 0; k < 4; k++) {
        int i = base + k;
        if (i < N) s += deg[i];
    }
    sd[t] = s;
    __syncthreads();
    for (int off = 128; off > 0; off >>= 1) {
        if (t < off) sd[t] += sd[t + off];
        __syncthreads();
    }
    if (t == 0) partials[blockIdx.x] = sd[0];
}

__global__ void scan_partials_kernel(const int* __restrict__ partials, int* __restrict__ offsets,
                                     int* __restrict__ rowptr, int nblocks, int N) {
    __shared__ int sd[1024];
    int t = threadIdx.x;
    int v = (t < nblocks) ? partials[t] : 0;
    sd[t] = v;
    __syncthreads();
    for (int off = 1; off < 1024; off <<= 1) {
        int tv = (t >= off) ? sd[t - off] : 0;
        __syncthreads();
        sd[t] += tv;
        __syncthreads();
    }
    if (t < nblocks) offsets[t] = sd[t] - v;  // exclusive
    if (t == 1023) rowptr[N] = sd[1023];      // total = E
}

__global__ void scan_local_kernel(const int* __restrict__ deg, const int* __restrict__ offsets,
                                  int* __restrict__ rowptr, float* __restrict__ deg_inv, int N) {
    __shared__ int ssum[256];
    int t = threadIdx.x;
    int base = blockIdx.x * SCAN_ELEMS + t * 4;
    int v[4];
    int s = 0;
#pragma unroll
    for (int k = 0; k < 4; k++) {
        int i = base + k;
        v[k] = (i < N) ? deg[i] : 0;
        s += v[k];
    }
    ssum[t] = s;
    __syncthreads();
    for (int off = 1; off < 256; off <<= 1) {
        int tv = (t >= off) ? ssum[t - off] : 0;
        __syncthreads();
        ssum[t] += tv;
        __syncthreads();
    }
    int excl = ssum[t] - s + offsets[blockIdx.x];
#pragma unroll
    for (int k = 0; k < 4; k++) {
        int i = base + k;
        if (i < N) {
            rowptr[i] = excl;
            deg_inv[i] = 1.0f / fmaxf((float)v[k], 1.0f);
            excl += v[k];
        }
    }
}

__global__ void fill_kernel(const int* __restrict__ src, const int* __restrict__ dst,
                            const int* __restrict__ rowptr, int* __restrict__ fill,
                            int* __restrict__ csr, int E) {
    int e = blockIdx.x * blockDim.x + threadIdx.x;
    if (e < E) {
        int d = dst[e];
        int pos = rowptr[d] + atomicAdd(&fill[d], 1);
        csr[pos] = src[e];
    }
}

// ---------------- Lift: X=tanh(xWx+bx), Y=tanh(xWy+by) ----------------
// Writes fp32 state (float2 pairs) + fp8 mirror (ushort per channel).

#define LIFT_NODES 16

__global__ __launch_bounds__(192) void lift_kernel(
    const float* __restrict__ x,
    const float* __restrict__ Wx, const float* __restrict__ bx,
    const float* __restrict__ Wy, const float* __restrict__ by,
    float2* __restrict__ XY, unsigned short* __restrict__ F, int N) {
    __shared__ float sx[LIFT_NODES][CIN + 1];
    int t = threadIdx.x;
    int nbase = blockIdx.x * LIFT_NODES;
    int maxn = N - nbase;

    {
        const int row4 = CIN / 4;  // 32
        for (int i = t; i < LIFT_NODES * row4; i += blockDim.x) {
            int nl = i / row4;
            int c4 = i - nl * row4;
            float4 v = make_float4(0.f, 0.f, 0.f, 0.f);
            if (nl < maxn)
                v = ((const float4*)x)[(size_t)(nbase + nl) * row4 + c4];
            sx[nl][c4 * 4 + 0] = v.x;
            sx[nl][c4 * 4 + 1] = v.y;
            sx[nl][c4 * 4 + 2] = v.z;
            sx[nl][c4 * 4 + 3] = v.w;
        }
    }
    __syncthreads();

    int h = t % 48;
    int slot = t / 48;
    int h1 = h + 48;

    float accx0[4], accx1[4], accy0[4], accy1[4];
    float bx0 = bx[h], bx1 = bx[h1], by0 = by[h], by1 = by[h1];
#pragma unroll
    for (int k = 0; k < 4; k++) {
        accx0[k] = bx0; accx1[k] = bx1;
        accy0[k] = by0; accy1[k] = by1;
    }

    for (int c = 0; c < CIN; c++) {
        float wx0 = Wx[c * HDIM + h], wx1 = Wx[c * HDIM + h1];
        float wy0 = Wy[c * HDIM + h], wy1 = Wy[c * HDIM + h1];
#pragma unroll
        for (int k = 0; k < 4; k++) {
            float xv = sx[slot * 4 + k][c];
            accx0[k] = fmaf(xv, wx0, accx0[k]);
            accx1[k] = fmaf(xv, wx1, accx1[k]);
            accy0[k] = fmaf(xv, wy0, accy0[k]);
            accy1[k] = fmaf(xv, wy1, accy1[k]);
        }
    }

#pragma unroll
    for (int k = 0; k < 4; k++) {
        int nl = slot * 4 + k;
        int nd = nbase + nl;
        if (nl < maxn) {
            float x0 = tanhf(accx0[k]), y0 = tanhf(accy0[k]);
            float x1 = tanhf(accx1[k]), y1 = tanhf(accy1[k]);
            XY[(size_t)nd * HDIM + h]  = make_float2(x0, y0);
            XY[(size_t)nd * HDIM + h1] = make_float2(x1, y1);
            F[(size_t)nd * HDIM + h]  = pack_fp8_pair(x0, y0);
            F[(size_t)nd * HDIM + h1] = pack_fp8_pair(x1, y1);
        }
    }
}

// ---------------- Layer: mean agg + LV Euler update ----------------
// One wave per node. CSR indices preloaded 64-wide, broadcast via __shfl.
// Gathers read the fp8 mirror: lanes 0-47 each load one uint (channels
// 2l, 2l+1 as fp8 X,Y quads) -> one dword / 192 B per row. 8-edge unroll.
// Update reads the fp32 row, writes fp32 next + fp8 mirror (or, on the
// last layer, the bf16 mirror for the MFMA readout).

#define LWPB 4

__global__ __launch_bounds__(256) void layer_kernel(
    const unsigned* __restrict__ F, const float4* __restrict__ XY4,
    float4* __restrict__ XYn4, unsigned* __restrict__ Fn, unsigned* __restrict__ Mn,
    const int* __restrict__ rowptr, const int* __restrict__ csr,
    const float* __restrict__ deg_inv,
    const float* __restrict__ alpha, const float* __restrict__ beta,
    const float* __restrict__ gamma, const float* __restrict__ delta,
    int N) {
    int wave = threadIdx.x >> 6;
    int lane = threadIdx.x & 63;
    int node = blockIdx.x * LWPB + wave;
    if (node >= N) return;

    int beg = rowptr[node];
    int cnt = rowptr[node + 1] - beg;
    bool act = (lane < 48);

    // acc: channels 2*lane (ax0/ay0) and 2*lane+1 (ax1/ay1)
    float ax0 = 0.f, ay0 = 0.f, ax1 = 0.f, ay1 = 0.f;

#define UNPACK_ACC(u)                                                      \
    do {                                                                   \
        vfloat2 p0 = __builtin_amdgcn_cvt_pk_f32_fp8((int)(u), false);     \
        vfloat2 p1 = __builtin_amdgcn_cvt_pk_f32_fp8((int)(u), true);      \
        ax0 += p0.x; ay0 += p0.y; ax1 += p1.x; ay1 += p1.y;                \
    } while (0)

    for (int base = 0; base < cnt; base += 64) {
        int m = min(64, cnt - base);
        int sidx = (lane < m) ? csr[beg + base + lane] : 0;
        int j = 0;
        for (; j + 8 <= m; j += 8) {
            int s0 = __shfl(sidx, j);
            int s1 = __shfl(sidx, j + 1);
            int s2 = __shfl(sidx, j + 2);
            int s3 = __shfl(sidx, j + 3);
            int s4 = __shfl(sidx, j + 4);
            int s5 = __shfl(sidx, j + 5);
            int s6 = __shfl(sidx, j + 6);
            int s7 = __shfl(sidx, j + 7);
            if (act) {
                unsigned u0 = F[(size_t)s0 * 48 + lane];
                unsigned u1 = F[(size_t)s1 * 48 + lane];
                unsigned u2 = F[(size_t)s2 * 48 + lane];
                unsigned u3 = F[(size_t)s3 * 48 + lane];
                unsigned u4 = F[(size_t)s4 * 48 + lane];
                unsigned u5 = F[(size_t)s5 * 48 + lane];
                unsigned u6 = F[(size_t)s6 * 48 + lane];
                unsigned u7 = F[(size_t)s7 * 48 + lane];
                UNPACK_ACC(u0); UNPACK_ACC(u1); UNPACK_ACC(u2); UNPACK_ACC(u3);
                UNPACK_ACC(u4); UNPACK_ACC(u5); UNPACK_ACC(u6); UNPACK_ACC(u7);
            }
        }
        for (; j < m; j++) {
            int s = __shfl(sidx, j);
            if (act) {
                unsigned u = F[(size_t)s * 48 + lane];
                UNPACK_ACC(u);
            }
        }
    }
#undef UNPACK_ACC

    float dinv = deg_inv[node];
    if (act) {
        ax0 *= dinv; ay0 *= dinv; ax1 *= dinv; ay1 *= dinv;
        float2 a2 = ((const float2*)alpha)[lane];
        float2 b2 = ((const float2*)beta)[lane];
        float2 g2 = ((const float2*)gamma)[lane];
        float2 d2 = ((const float2*)delta)[lane];
        float4 v = XY4[(size_t)node * 48 + lane];
        float4 o;
        o.x = v.x + DTC * v.x * (a2.x - b2.x * ay0);
        o.y = v.y + DTC * v.y * (-g2.x + d2.x * ax0);
        o.z = v.z + DTC * v.z * (a2.y - b2.y * ay1);
        o.w = v.w + DTC * v.w * (-g2.y + d2.y * ax1);
        XYn4[(size_t)node * 48 + lane] = o;
        if (Fn)
            Fn[(size_t)node * 48 + lane] = pack_fp8_quad(o.x, o.y, o.z, o.w);
        if (Mn)
            ((uint2*)(Mn + (size_t)node * HDIM))[lane] =
                make_uint2(pack_bf16_pair(o.x, o.y), pack_bf16_pair(o.z, o.w));
    }
}

// ---------------- Readout: out = [X,Y] @ Wr + br via MFMA ----------------
// A = bf16 mirror rows (k interleaved: k=2h -> X[h], k=2h+1 -> Y[h]).
// B = WgT bf16 in LDS, [48 padded cols][192 k] with k in the SAME
// interleaved order, row stride 200 ushorts (bank spread for b128).
// Block = 256 (4 waves); wave = 16-node M-tile x 3 N-tiles x K=192 (6 steps).

#define WG_STRIDE 200

__global__ __launch_bounds__(256) void readout_mfma_kernel(
    const unsigned short* __restrict__ mb, const float* __restrict__ Wr,
    const float* __restrict__ br, float* __restrict__ out, int N) {
    __shared__ unsigned short sW[48 * WG_STRIDE];  // 19200 B
    __shared__ float sB[48];
    int t = threadIdx.x;

    for (int i = t; i < 48 * 192; i += 256) {
        int n = i / 192;
        int kk = i - n * 192;
        int h = kk >> 1;
        float w = 0.f;
        if (n < COUT) w = (kk & 1) ? Wr[(HDIM + h) * COUT + n] : Wr[h * COUT + n];
        unsigned uw = __float_as_uint(w);
        uw = (uw + 0x7fffu + ((uw >> 16) & 1u)) >> 16;  // RNE bf16
        sW[n * WG_STRIDE + kk] = (unsigned short)uw;
    }
    if (t < 48) sB[t] = (t < COUT) ? br[t] : 0.f;
    __syncthreads();

    int wv = t >> 6;
    int lane = t & 63;
    int quad = lane >> 4;
    int m = lane & 15;
    int mbase = blockIdx.x * 64 + wv * 16;

    int anode = mbase + m;
    if (anode >= N) anode = N - 1;  // clamp (dup rows; stores guarded)
    const unsigned short* arow = mb + (size_t)anode * 192;

    vfloat4 acc0 = {0.f, 0.f, 0.f, 0.f};
    vfloat4 acc1 = {0.f, 0.f, 0.f, 0.f};
    vfloat4 acc2 = {0.f, 0.f, 0.f, 0.f};

#pragma unroll
    for (int kt = 0; kt < 6; kt++) {
        int k0 = kt * 32 + quad * 8;
        vshort8 a = *(const vshort8*)(arow + k0);
        vshort8 b0 = *(const vshort8*)&sW[(0 * 16 + m) * WG_STRIDE + k0];
        vshort8 b1 = *(const vshort8*)&sW[(1 * 16 + m) * WG_STRIDE + k0];
        vshort8 b2 = *(const vshort8*)&sW[(2 * 16 + m) * WG_STRIDE + k0];
        acc0 = __builtin_amdgcn_mfma_f32_16x16x32_bf16(a, b0, acc0, 0, 0, 0);
        acc1 = __builtin_amdgcn_mfma_f32_16x16x32_bf16(a, b1, acc1, 0, 0, 0);
        acc2 = __builtin_amdgcn_mfma_f32_16x16x32_bf16(a, b2, acc2, 0, 0, 0);
    }

    // C/D: col = lane&15 (= output within tile), row = quad*4+reg (= node)
    float bo0 = sB[m];
    float bo1 = sB[16 + m];
    float bo2 = (m < 8) ? sB[32 + m] : 0.f;
#pragma unroll
    for (int r = 0; r < 4; r++) {
        int node = mbase + quad * 4 + r;
        if (node < N) {
            float* orow = out + (size_t)node * COUT;
            orow[m] = acc0[r] + bo0;
            orow[16 + m] = acc1[r] + bo1;
            if (m < 8) orow[32 + m] = acc2[r] + bo2;
        }
    }
}

// ---------------- launch ----------------

extern "C" void kernel_launch(void* const* d_in, const int* in_sizes, int n_in,
                              void* d_out, int out_size, void* d_ws, size_t ws_size,
                              hipStream_t stream) {
    const float* x     = (const float*)d_in[0];
    const int*   ei    = (const int*)d_in[1];
    const float* Wx    = (const float*)d_in[2];
    const float* bx    = (const float*)d_in[3];
    const float* Wy    = (const float*)d_in[4];
    const float* by    = (const float*)d_in[5];
    const float* alpha = (const float*)d_in[6];
    const float* beta  = (const float*)d_in[7];
    const float* gamma = (const float*)d_in[8];
    const float* delta = (const float*)d_in[9];
    const float* Wr    = (const float*)d_in[10];
    const float* br    = (const float*)d_in[11];

    const int N = in_sizes[0] / CIN;
    const int E = in_sizes[1] / 2;
    const int nscan = (N + SCAN_ELEMS - 1) / SCAN_ELEMS;  // 49 for N=50000

    char* ws = (char*)d_ws;
    size_t off = 0;
    auto alloc = [&](size_t bytes) -> void* {
        off = (off + 255) & ~(size_t)255;
        void* p = ws + off;
        off += bytes;
        return p;
    };
    int* deg       = (int*)alloc((size_t)2 * N * sizeof(int));  // deg + fill
    int* fill      = deg + N;
    int* rowptr    = (int*)alloc((size_t)(N + 1) * sizeof(int));
    int* csr       = (int*)alloc((size_t)E * sizeof(int));
    float* dinv    = (float*)alloc((size_t)N * sizeof(float));
    int* partials  = (int*)alloc((size_t)nscan * sizeof(int));
    int* offsets   = (int*)alloc((size_t)nscan * sizeof(int));
    float2* XYa    = (float2*)alloc((size_t)N * HDIM * sizeof(float2));
    float2* XYb    = (float2*)alloc((size_t)N * HDIM * sizeof(float2));
    unsigned* Fa   = (unsigned*)alloc((size_t)N * 48 * sizeof(unsigned));   // fp8 mirror
    unsigned* Fb   = (unsigned*)alloc((size_t)N * 48 * sizeof(unsigned));
    unsigned* Mb16 = (unsigned*)alloc((size_t)N * HDIM * sizeof(unsigned)); // bf16 mirror
    (void)ws_size;

    const int* e_src = ei;
    const int* e_dst = ei + E;

    hipMemsetAsync(deg, 0, (size_t)2 * N * sizeof(int), stream);

    count_kernel<<<(E + 255) / 256, 256, 0, stream>>>(e_dst, deg, E);
    scan_reduce_kernel<<<nscan, 256, 0, stream>>>(deg, partials, N);
    scan_partials_kernel<<<1, 1024, 0, stream>>>(partials, offsets, rowptr, nscan, N);
    scan_local_kernel<<<nscan, 256, 0, stream>>>(deg, offsets, rowptr, dinv, N);
    fill_kernel<<<(E + 255) / 256, 256, 0, stream>>>(e_src, e_dst, rowptr, fill, csr, E);

    lift_kernel<<<(N + LIFT_NODES - 1) / LIFT_NODES, 192, 0, stream>>>(
        x, Wx, bx, Wy, by, XYa, (unsigned short*)Fa, N);

    const float2* XYc = XYa;
    float2* XYn = XYb;
    const unsigned* Fc = Fa;
    unsigned* Fnx = Fb;
    for (int l = 0; l < NLAYER; l++) {
        bool last = (l == NLAYER - 1);
        layer_kernel<<<(N + LWPB - 1) / LWPB, LWPB * 64, 0, stream>>>(
            Fc, (const float4*)XYc, (float4*)XYn,
            last ? (unsigned*)nullptr : Fnx,
            last ? Mb16 : (unsigned*)nullptr,
            rowptr, csr, dinv,
            alpha + l * HDIM, beta + l * HDIM, gamma + l * HDIM, delta + l * HDIM, N);
        const float2* t2 = XYc; XYc = XYn; XYn = (float2*)t2;
        const unsigned* tf = Fc; Fc = Fnx; Fnx = (unsigned*)tf;
    }

    readout_mfma_kernel<<<(N + 63) / 64, 256, 0, stream>>>(
        (const unsigned short*)Mb16, Wr, br, (float*)d_out, N);
}

// Round 6
// 411.542 us; speedup vs baseline: 2.6013x; 1.0760x over previous
//
#include <hip/hip_runtime.h>
#include <hip/hip_bf16.h>

// PPGNN: lift -> 5x (mean-aggregate + Lotka-Volterra Euler step) -> readout
// N=50000, E=800000, C_IN=128, H=96, C_OUT=40, L=5, DT=0.05
//
// fp32 master state XY (flat [node][192], cc even = X[cc/2], odd = Y[cc/2]).
// Mirrors: fp8 e4m3 F (uint = 4 fp8 = X,Y,X,Y for 2 channels; row 192 B)
// gathered by layers; bf16 Mb16 (row 384 B) written by last layer, consumed
// by MFMA readout. Lift is now an MFMA GEMM [N,128]x[128,192] in bf16 with
// fused tanh + fp8-pack epilogue (was VALU-bound fp32 at ~72 us).

#define HDIM 96
#define CIN 128
#define COUT 40
#define NLAYER 5
#define DTC 0.05f

typedef float  vfloat2 __attribute__((ext_vector_type(2)));
typedef float  vfloat4 __attribute__((ext_vector_type(4)));
typedef short  vshort8 __attribute__((ext_vector_type(8)));

__device__ __forceinline__ unsigned bf16_rne(float f) {
    unsigned u = __float_as_uint(f);
    return (u + 0x7fffu + ((u >> 16) & 1u)) >> 16;
}

__device__ __forceinline__ unsigned pack_bf16_pair(float xf, float yf) {
    return bf16_rne(xf) | (bf16_rne(yf) << 16);
}

__device__ __forceinline__ unsigned pack_fp8_quad(float x0, float y0, float x1, float y1) {
    int lo = __builtin_amdgcn_cvt_pk_fp8_f32(x0, y0, 0, false);
    int full = __builtin_amdgcn_cvt_pk_fp8_f32(x1, y1, lo, true);
    return (unsigned)full;
}

// ---------------- CSR build ----------------

__global__ void count_kernel(const int* __restrict__ dst, int* __restrict__ deg, int E) {
    int e = blockIdx.x * blockDim.x + threadIdx.x;
    if (e < E) atomicAdd(&deg[dst[e]], 1);
}

#define SCAN_ELEMS 1024

__global__ void scan_reduce_kernel(const int* __restrict__ deg, int* __restrict__ partials, int N) {
    __shared__ int sd[256];
    int t = threadIdx.x;
    int base = blockIdx.x * SCAN_ELEMS + t * 4;
    int s = 0;
#pragma unroll
    for (int k = 0; k < 4; k++) {
        int i = base + k;
        if (i < N) s += deg[i];
    }
    sd[t] = s;
    __syncthreads();
    for (int off = 128; off > 0; off >>= 1) {
        if (t < off) sd[t] += sd[t + off];
        __syncthreads();
    }
    if (t == 0) partials[blockIdx.x] = sd[0];
}

__global__ void scan_partials_kernel(const int* __restrict__ partials, int* __restrict__ offsets,
                                     int* __restrict__ rowptr, int nblocks, int N) {
    __shared__ int sd[1024];
    int t = threadIdx.x;
    int v = (t < nblocks) ? partials[t] : 0;
    sd[t] = v;
    __syncthreads();
    for (int off = 1; off < 1024; off <<= 1) {
        int tv = (t >= off) ? sd[t - off] : 0;
        __syncthreads();
        sd[t] += tv;
        __syncthreads();
    }
    if (t < nblocks) offsets[t] = sd[t] - v;  // exclusive
    if (t == 1023) rowptr[N] = sd[1023];      // total = E
}

__global__ void scan_local_kernel(const int* __restrict__ deg, const int* __restrict__ offsets,
                                  int* __restrict__ rowptr, float* __restrict__ deg_inv, int N) {
    __shared__ int ssum[256];
    int t = threadIdx.x;
    int base = blockIdx.x * SCAN_ELEMS + t * 4;
    int v[4];
    int s = 0;
#pragma unroll
    for (int k = 0; k < 4; k++) {
        int i = base + k;
        v[k] = (i < N) ? deg[i] : 0;
        s += v[k];
    }
    ssum[t] = s;
    __syncthreads();
    for (int off = 1; off < 256; off <<= 1) {
        int tv = (t >= off) ? ssum[t - off] : 0;
        __syncthreads();
        ssum[t] += tv;
        __syncthreads();
    }
    int excl = ssum[t] - s + offsets[blockIdx.x];
#pragma unroll
    for (int k = 0; k < 4; k++) {
        int i = base + k;
        if (i < N) {
            rowptr[i] = excl;
            deg_inv[i] = 1.0f / fmaxf((float)v[k], 1.0f);
            excl += v[k];
        }
    }
}

__global__ void fill_kernel(const int* __restrict__ src, const int* __restrict__ dst,
                            const int* __restrict__ rowptr, int* __restrict__ fill,
                            int* __restrict__ csr, int E) {
    int e = blockIdx.x * blockDim.x + threadIdx.x;
    if (e < E) {
        int d = dst[e];
        int pos = rowptr[d] + atomicAdd(&fill[d], 1);
        csr[pos] = src[e];
    }
}

// ---------------- Weight prep: Wx,Wy fp32 -> interleaved bf16 WcT + bias ----

__global__ __launch_bounds__(256) void wprep_kernel(
    const float* __restrict__ Wx, const float* __restrict__ bx,
    const float* __restrict__ Wy, const float* __restrict__ by,
    unsigned short* __restrict__ WcT, float* __restrict__ bc) {
    int t = blockIdx.x * blockDim.x + threadIdx.x;
    if (t < 192 * 128) {
        int cc = t >> 7;
        int k = t & 127;
        int h = cc >> 1;
        float w = (cc & 1) ? Wy[k * HDIM + h] : Wx[k * HDIM + h];
        WcT[cc * 128 + k] = (unsigned short)bf16_rne(w);
    }
    if (t < 192) {
        int h = t >> 1;
        bc[t] = (t & 1) ? by[h] : bx[h];
    }
}

// ---------------- Lift (MFMA): tanh(x @ [Wx|Wy] + b) ----------------
// Block = 256 (4 waves), 64 nodes/block. WcT staged in LDS with stride 136
// ushorts (272 B: 16B-aligned for ds_read_b128, 2-way bank alias = free).
// Wave: M-tile 16 nodes x 12 N-tiles(16cc) x K=128 (4 MFMA steps).
// Epilogue: +bias, tanh, fp32 state store, fp8 quad pack via 2x shfl_xor.

#define LW_STRIDE 136

__global__ __launch_bounds__(256) void lift_mfma_kernel(
    const float* __restrict__ x, const unsigned short* __restrict__ WcT,
    const float* __restrict__ bc, float* __restrict__ XYf,
    unsigned* __restrict__ F, int N) {
    __shared__ unsigned short sW[192 * LW_STRIDE];  // 52224 B
    __shared__ float sBc[192];
    int t = threadIdx.x;

    {
        const unsigned* g = (const unsigned*)WcT;  // 192*64 uints
        unsigned* s = (unsigned*)sW;
        for (int i = t; i < 192 * 64; i += 256) {
            int cc = i >> 6;
            int kp = i & 63;
            s[cc * (LW_STRIDE / 2) + kp] = g[i];
        }
    }
    if (t < 192) sBc[t] = bc[t];
    __syncthreads();

    int wv = t >> 6;
    int lane = t & 63;
    int quad = lane >> 4;
    int m = lane & 15;
    int mbase = blockIdx.x * 64 + wv * 16;

    int anode = mbase + m;
    if (anode >= N) anode = N - 1;  // clamp; stores guarded
    const float* xrow = x + (size_t)anode * CIN;

    vfloat4 acc[12];
#pragma unroll
    for (int i = 0; i < 12; i++) acc[i] = (vfloat4){0.f, 0.f, 0.f, 0.f};

#pragma unroll
    for (int kt = 0; kt < 4; kt++) {
        int k0 = kt * 32 + quad * 8;
        float4 xa = *(const float4*)(xrow + k0);
        float4 xb = *(const float4*)(xrow + k0 + 4);
        uint4 ua;
        ua.x = pack_bf16_pair(xa.x, xa.y);
        ua.y = pack_bf16_pair(xa.z, xa.w);
        ua.z = pack_bf16_pair(xb.x, xb.y);
        ua.w = pack_bf16_pair(xb.z, xb.w);
        vshort8 a = *(vshort8*)&ua;
#pragma unroll
        for (int nt = 0; nt < 12; nt++) {
            vshort8 b = *(const vshort8*)&sW[(nt * 16 + m) * LW_STRIDE + k0];
            acc[nt] = __builtin_amdgcn_mfma_f32_16x16x32_bf16(a, b, acc[nt], 0, 0, 0);
        }
    }

    // C/D: row(node) = quad*4+reg, col(cc within tile) = lane&15
#pragma unroll
    for (int nt = 0; nt < 12; nt++) {
        int ccb = nt * 16 + m;
        float bco = sBc[ccb];
#pragma unroll
        for (int r = 0; r < 4; r++) {
            int node = mbase + quad * 4 + r;
            float v = tanhf(acc[nt][r] + bco);
            // fp8 pack: lanes m, m^1 -> pair; m, m^2 -> quad (even m = X channel)
            unsigned u = (unsigned)(__builtin_amdgcn_cvt_pk_fp8_f32(
                             v, __shfl_xor(v, 1), 0, false) & 0xffff);
            unsigned w = u | (((unsigned)__shfl_xor((int)u, 2)) << 16);
            if (node < N) {
                XYf[(size_t)node * 192 + ccb] = v;
                if ((m & 3) == 0) F[(size_t)node * 48 + (ccb >> 2)] = w;
            }
        }
    }
}

// ---------------- Layer: mean agg + LV Euler update ----------------
// One wave per node. CSR indices preloaded 64-wide, broadcast via __shfl.
// Gathers read the fp8 mirror (one dword / 192 B per row). 8-edge unroll.
// Update reads fp32 row, writes fp32 next + fp8 mirror (last layer: bf16
// mirror for MFMA readout instead).

#define LWPB 4

__global__ __launch_bounds__(256) void layer_kernel(
    const unsigned* __restrict__ F, const float4* __restrict__ XY4,
    float4* __restrict__ XYn4, unsigned* __restrict__ Fn, unsigned* __restrict__ Mn,
    const int* __restrict__ rowptr, const int* __restrict__ csr,
    const float* __restrict__ deg_inv,
    const float* __restrict__ alpha, const float* __restrict__ beta,
    const float* __restrict__ gamma, const float* __restrict__ delta,
    int N) {
    int wave = threadIdx.x >> 6;
    int lane = threadIdx.x & 63;
    int node = blockIdx.x * LWPB + wave;
    if (node >= N) return;

    int beg = rowptr[node];
    int cnt = rowptr[node + 1] - beg;
    bool act = (lane < 48);

    float ax0 = 0.f, ay0 = 0.f, ax1 = 0.f, ay1 = 0.f;

#define UNPACK_ACC(u)                                                      \
    do {                                                                   \
        vfloat2 p0 = __builtin_amdgcn_cvt_pk_f32_fp8((int)(u), false);     \
        vfloat2 p1 = __builtin_amdgcn_cvt_pk_f32_fp8((int)(u), true);      \
        ax0 += p0.x; ay0 += p0.y; ax1 += p1.x; ay1 += p1.y;                \
    } while (0)

    for (int base = 0; base < cnt; base += 64) {
        int m = min(64, cnt - base);
        int sidx = (lane < m) ? csr[beg + base + lane] : 0;
        int j = 0;
        for (; j + 8 <= m; j += 8) {
            int s0 = __shfl(sidx, j);
            int s1 = __shfl(sidx, j + 1);
            int s2 = __shfl(sidx, j + 2);
            int s3 = __shfl(sidx, j + 3);
            int s4 = __shfl(sidx, j + 4);
            int s5 = __shfl(sidx, j + 5);
            int s6 = __shfl(sidx, j + 6);
            int s7 = __shfl(sidx, j + 7);
            if (act) {
                unsigned u0 = F[(size_t)s0 * 48 + lane];
                unsigned u1 = F[(size_t)s1 * 48 + lane];
                unsigned u2 = F[(size_t)s2 * 48 + lane];
                unsigned u3 = F[(size_t)s3 * 48 + lane];
                unsigned u4 = F[(size_t)s4 * 48 + lane];
                unsigned u5 = F[(size_t)s5 * 48 + lane];
                unsigned u6 = F[(size_t)s6 * 48 + lane];
                unsigned u7 = F[(size_t)s7 * 48 + lane];
                UNPACK_ACC(u0); UNPACK_ACC(u1); UNPACK_ACC(u2); UNPACK_ACC(u3);
                UNPACK_ACC(u4); UNPACK_ACC(u5); UNPACK_ACC(u6); UNPACK_ACC(u7);
            }
        }
        for (; j < m; j++) {
            int s = __shfl(sidx, j);
            if (act) {
                unsigned u = F[(size_t)s * 48 + lane];
                UNPACK_ACC(u);
            }
        }
    }
#undef UNPACK_ACC

    float dinv = deg_inv[node];
    if (act) {
        ax0 *= dinv; ay0 *= dinv; ax1 *= dinv; ay1 *= dinv;
        float2 a2 = ((const float2*)alpha)[lane];
        float2 b2 = ((const float2*)beta)[lane];
        float2 g2 = ((const float2*)gamma)[lane];
        float2 d2 = ((const float2*)delta)[lane];
        float4 v = XY4[(size_t)node * 48 + lane];
        float4 o;
        o.x = v.x + DTC * v.x * (a2.x - b2.x * ay0);
        o.y = v.y + DTC * v.y * (-g2.x + d2.x * ax0);
        o.z = v.z + DTC * v.z * (a2.y - b2.y * ay1);
        o.w = v.w + DTC * v.w * (-g2.y + d2.y * ax1);
        XYn4[(size_t)node * 48 + lane] = o;
        if (Fn)
            Fn[(size_t)node * 48 + lane] = pack_fp8_quad(o.x, o.y, o.z, o.w);
        if (Mn)
            ((uint2*)(Mn + (size_t)node * HDIM))[lane] =
                make_uint2(pack_bf16_pair(o.x, o.y), pack_bf16_pair(o.z, o.w));
    }
}

// ---------------- Readout: out = [X,Y] @ Wr + br via MFMA ----------------

#define WG_STRIDE 200

__global__ __launch_bounds__(256) void readout_mfma_kernel(
    const unsigned short* __restrict__ mb, const float* __restrict__ Wr,
    const float* __restrict__ br, float* __restrict__ out, int N) {
    __shared__ unsigned short sW[48 * WG_STRIDE];
    __shared__ float sB[48];
    int t = threadIdx.x;

    for (int i = t; i < 48 * 192; i += 256) {
        int n = i / 192;
        int kk = i - n * 192;
        int h = kk >> 1;
        float w = 0.f;
        if (n < COUT) w = (kk & 1) ? Wr[(HDIM + h) * COUT + n] : Wr[h * COUT + n];
        sW[n * WG_STRIDE + kk] = (unsigned short)bf16_rne(w);
    }
    if (t < 48) sB[t] = (t < COUT) ? br[t] : 0.f;
    __syncthreads();

    int wv = t >> 6;
    int lane = t & 63;
    int quad = lane >> 4;
    int m = lane & 15;
    int mbase = blockIdx.x * 64 + wv * 16;

    int anode = mbase + m;
    if (anode >= N) anode = N - 1;
    const unsigned short* arow = mb + (size_t)anode * 192;

    vfloat4 acc0 = {0.f, 0.f, 0.f, 0.f};
    vfloat4 acc1 = {0.f, 0.f, 0.f, 0.f};
    vfloat4 acc2 = {0.f, 0.f, 0.f, 0.f};

#pragma unroll
    for (int kt = 0; kt < 6; kt++) {
        int k0 = kt * 32 + quad * 8;
        vshort8 a = *(const vshort8*)(arow + k0);
        vshort8 b0 = *(const vshort8*)&sW[(0 * 16 + m) * WG_STRIDE + k0];
        vshort8 b1 = *(const vshort8*)&sW[(1 * 16 + m) * WG_STRIDE + k0];
        vshort8 b2 = *(const vshort8*)&sW[(2 * 16 + m) * WG_STRIDE + k0];
        acc0 = __builtin_amdgcn_mfma_f32_16x16x32_bf16(a, b0, acc0, 0, 0, 0);
        acc1 = __builtin_amdgcn_mfma_f32_16x16x32_bf16(a, b1, acc1, 0, 0, 0);
        acc2 = __builtin_amdgcn_mfma_f32_16x16x32_bf16(a, b2, acc2, 0, 0, 0);
    }

    float bo0 = sB[m];
    float bo1 = sB[16 + m];
    float bo2 = (m < 8) ? sB[32 + m] : 0.f;
#pragma unroll
    for (int r = 0; r < 4; r++) {
        int node = mbase + quad * 4 + r;
        if (node < N) {
            float* orow = out + (size_t)node * COUT;
            orow[m] = acc0[r] + bo0;
            orow[16 + m] = acc1[r] + bo1;
            if (m < 8) orow[32 + m] = acc2[r] + bo2;
        }
    }
}

// ---------------- launch ----------------

extern "C" void kernel_launch(void* const* d_in, const int* in_sizes, int n_in,
                              void* d_out, int out_size, void* d_ws, size_t ws_size,
                              hipStream_t stream) {
    const float* x     = (const float*)d_in[0];
    const int*   ei    = (const int*)d_in[1];
    const float* Wx    = (const float*)d_in[2];
    const float* bx    = (const float*)d_in[3];
    const float* Wy    = (const float*)d_in[4];
    const float* by    = (const float*)d_in[5];
    const float* alpha = (const float*)d_in[6];
    const float* beta  = (const float*)d_in[7];
    const float* gamma = (const float*)d_in[8];
    const float* delta = (const float*)d_in[9];
    const float* Wr    = (const float*)d_in[10];
    const float* br    = (const float*)d_in[11];

    const int N = in_sizes[0] / CIN;
    const int E = in_sizes[1] / 2;
    const int nscan = (N + SCAN_ELEMS - 1) / SCAN_ELEMS;  // 49 for N=50000

    char* ws = (char*)d_ws;
    size_t off = 0;
    auto alloc = [&](size_t bytes) -> void* {
        off = (off + 255) & ~(size_t)255;
        void* p = ws + off;
        off += bytes;
        return p;
    };
    int* deg       = (int*)alloc((size_t)2 * N * sizeof(int));  // deg + fill
    int* fill      = deg + N;
    int* rowptr    = (int*)alloc((size_t)(N + 1) * sizeof(int));
    int* csr       = (int*)alloc((size_t)E * sizeof(int));
    float* dinv    = (float*)alloc((size_t)N * sizeof(float));
    int* partials  = (int*)alloc((size_t)nscan * sizeof(int));
    int* offsets   = (int*)alloc((size_t)nscan * sizeof(int));
    float* XYa     = (float*)alloc((size_t)N * 192 * sizeof(float));
    float* XYb     = (float*)alloc((size_t)N * 192 * sizeof(float));
    unsigned* Fa   = (unsigned*)alloc((size_t)N * 48 * sizeof(unsigned));   // fp8 mirror
    unsigned* Fb   = (unsigned*)alloc((size_t)N * 48 * sizeof(unsigned));
    unsigned* Mb16 = (unsigned*)alloc((size_t)N * HDIM * sizeof(unsigned)); // bf16 mirror
    unsigned short* WcT = (unsigned short*)alloc((size_t)192 * 128 * sizeof(unsigned short));
    float* bc      = (float*)alloc((size_t)192 * sizeof(float));
    (void)ws_size;

    const int* e_src = ei;
    const int* e_dst = ei + E;

    hipMemsetAsync(deg, 0, (size_t)2 * N * sizeof(int), stream);

    count_kernel<<<(E + 255) / 256, 256, 0, stream>>>(e_dst, deg, E);
    scan_reduce_kernel<<<nscan, 256, 0, stream>>>(deg, partials, N);
    scan_partials_kernel<<<1, 1024, 0, stream>>>(partials, offsets, rowptr, nscan, N);
    scan_local_kernel<<<nscan, 256, 0, stream>>>(deg, offsets, rowptr, dinv, N);
    fill_kernel<<<(E + 255) / 256, 256, 0, stream>>>(e_src, e_dst, rowptr, fill, csr, E);

    wprep_kernel<<<(192 * 128 + 255) / 256, 256, 0, stream>>>(Wx, bx, Wy, by, WcT, bc);
    lift_mfma_kernel<<<(N + 63) / 64, 256, 0, stream>>>(x, WcT, bc, XYa, Fa, N);

    const float* XYc = XYa;
    float* XYn = XYb;
    const unsigned* Fc = Fa;
    unsigned* Fnx = Fb;
    for (int l = 0; l < NLAYER; l++) {
        bool last = (l == NLAYER - 1);
        layer_kernel<<<(N + LWPB - 1) / LWPB, LWPB * 64, 0, stream>>>(
            Fc, (const float4*)XYc, (float4*)XYn,
            last ? (unsigned*)nullptr : Fnx,
            last ? Mb16 : (unsigned*)nullptr,
            rowptr, csr, dinv,
            alpha + l * HDIM, beta + l * HDIM, gamma + l * HDIM, delta + l * HDIM, N);
        const float* t2 = XYc; XYc = XYn; XYn = (float*)t2;
        const unsigned* tf = Fc; Fc = Fnx; Fnx = (unsigned*)tf;
    }

    readout_mfma_kernel<<<(N + 63) / 64, 256, 0, stream>>>(
        (const unsigned short*)Mb16, Wr, br, (float*)d_out, N);
}

// Round 7
// 368.160 us; speedup vs baseline: 2.9078x; 1.1178x over previous
//
#include <hip/hip_runtime.h>
#include <hip/hip_bf16.h>

// PPGNN: lift -> 5x (mean-aggregate + Lotka-Volterra Euler step) -> readout
// N=50000, E=800000, C_IN=128, H=96, C_OUT=40, L=5, DT=0.05
//
// fp32 master state XY (flat [node][192], cc even = X[cc/2], odd = Y[cc/2]).
// Mirrors: fp8 e4m3 F (uint = 4 fp8 for 2 channel pairs; row 192 B) gathered
// by layers; bf16 Mb16 written by last layer, consumed by MFMA readout.
// Lift + readout are bf16 MFMA GEMMs.
// CSR build is a two-level bucket build (no per-edge global atomics, no
// cross-XCD write amplification): coarse 128-node buckets -> per-bucket CSR.

#define HDIM 96
#define CIN 128
#define COUT 40
#define NLAYER 5
#define DTC 0.05f

#define BK_SHIFT 7
#define BK_SIZE 128
#define EPB 4096   // edges per block in bucket hist/scatter

typedef float  vfloat2 __attribute__((ext_vector_type(2)));
typedef float  vfloat4 __attribute__((ext_vector_type(4)));
typedef short  vshort8 __attribute__((ext_vector_type(8)));

__device__ __forceinline__ unsigned bf16_rne(float f) {
    unsigned u = __float_as_uint(f);
    return (u + 0x7fffu + ((u >> 16) & 1u)) >> 16;
}

__device__ __forceinline__ unsigned pack_bf16_pair(float xf, float yf) {
    return bf16_rne(xf) | (bf16_rne(yf) << 16);
}

__device__ __forceinline__ unsigned pack_fp8_quad(float x0, float y0, float x1, float y1) {
    int lo = __builtin_amdgcn_cvt_pk_fp8_f32(x0, y0, 0, false);
    int full = __builtin_amdgcn_cvt_pk_fp8_f32(x1, y1, lo, true);
    return (unsigned)full;
}

// ---------------- CSR build (bucketed, atomic-light) ----------------

__global__ __launch_bounds__(256) void bhist_kernel(const int* __restrict__ dst,
                                                    int* __restrict__ ghist, int E, int NB) {
    __shared__ int h[512];
    for (int i = threadIdx.x; i < NB; i += 256) h[i] = 0;
    __syncthreads();
    int base = blockIdx.x * EPB;
    int end = min(E, base + EPB);
    for (int e = base + threadIdx.x; e < end; e += 256)
        atomicAdd(&h[dst[e] >> BK_SHIFT], 1);
    __syncthreads();
    for (int i = threadIdx.x; i < NB; i += 256)
        if (h[i]) atomicAdd(&ghist[i], h[i]);
}

__global__ void bscan_kernel(const int* __restrict__ ghist, int* __restrict__ bbase,
                             int* __restrict__ bcursor, int* __restrict__ rowptr,
                             int NB, int N, int E) {
    __shared__ int sd[512];
    int t = threadIdx.x;
    int v = (t < NB) ? ghist[t] : 0;
    sd[t] = v;
    __syncthreads();
    for (int off = 1; off < 512; off <<= 1) {
        int tv = (t >= off) ? sd[t - off] : 0;
        __syncthreads();
        sd[t] += tv;
        __syncthreads();
    }
    if (t < NB) {
        int b = sd[t] - v;  // exclusive
        bbase[t] = b;
        bcursor[t] = b;
    }
    if (t == 0) { bbase[NB] = E; rowptr[N] = E; }
}

__global__ __launch_bounds__(256) void bscatter_kernel(
    const int* __restrict__ src, const int* __restrict__ dst,
    int* __restrict__ bcursor, unsigned* __restrict__ packed, int E, int NB) {
    __shared__ int h[512];
    __shared__ int cur[512];
    for (int i = threadIdx.x; i < NB; i += 256) h[i] = 0;
    __syncthreads();
    int base = blockIdx.x * EPB;
    int end = min(E, base + EPB);
    for (int e = base + threadIdx.x; e < end; e += 256)
        atomicAdd(&h[dst[e] >> BK_SHIFT], 1);
    __syncthreads();
    for (int i = threadIdx.x; i < NB; i += 256)
        cur[i] = h[i] ? atomicAdd(&bcursor[i], h[i]) : 0;
    __syncthreads();
    for (int e = base + threadIdx.x; e < end; e += 256) {
        int d = dst[e];
        int b = d >> BK_SHIFT;
        int pos = atomicAdd(&cur[b], 1);
        packed[pos] = (unsigned)src[e] | ((unsigned)(d & (BK_SIZE - 1)) << 17);
    }
}

__global__ __launch_bounds__(256) void bcsr_kernel(
    const unsigned* __restrict__ packed, const int* __restrict__ bbase,
    int* __restrict__ rowptr, float* __restrict__ dinv, int* __restrict__ csr,
    int N, int NB) {
    __shared__ int ldeg[BK_SIZE];
    __shared__ int sscan[BK_SIZE];
    __shared__ int lcur[BK_SIZE];
    int b = blockIdx.x;
    int t = threadIdx.x;
    int lo = bbase[b], hi = bbase[b + 1];
    if (t < BK_SIZE) ldeg[t] = 0;
    __syncthreads();
    for (int e = lo + t; e < hi; e += 256)
        atomicAdd(&ldeg[(packed[e] >> 17) & (BK_SIZE - 1)], 1);
    __syncthreads();
    if (t < BK_SIZE) sscan[t] = ldeg[t];
    __syncthreads();
    for (int off = 1; off < BK_SIZE; off <<= 1) {
        int tv = (t < BK_SIZE && t >= off) ? sscan[t - off] : 0;
        __syncthreads();
        if (t < BK_SIZE) sscan[t] += tv;
        __syncthreads();
    }
    if (t < BK_SIZE) {
        int excl = sscan[t] - ldeg[t];
        int gpos = lo + excl;
        lcur[t] = gpos;
        int node = b * BK_SIZE + t;
        if (node < N) {
            rowptr[node] = gpos;
            dinv[node] = 1.0f / fmaxf((float)ldeg[t], 1.0f);
        }
    }
    __syncthreads();
    for (int e = lo + t; e < hi; e += 256) {
        unsigned p = packed[e];
        int l = (p >> 17) & (BK_SIZE - 1);
        int pos = atomicAdd(&lcur[l], 1);
        csr[pos] = (int)(p & 0x1FFFFu);
    }
}

// ---------------- Weight prep: Wx,Wy fp32 -> interleaved bf16 WcT + bias ----

__global__ __launch_bounds__(256) void wprep_kernel(
    const float* __restrict__ Wx, const float* __restrict__ bx,
    const float* __restrict__ Wy, const float* __restrict__ by,
    unsigned short* __restrict__ WcT, float* __restrict__ bc) {
    int t = blockIdx.x * blockDim.x + threadIdx.x;
    if (t < 192 * 128) {
        int cc = t >> 7;
        int k = t & 127;
        int h = cc >> 1;
        float w = (cc & 1) ? Wy[k * HDIM + h] : Wx[k * HDIM + h];
        WcT[cc * 128 + k] = (unsigned short)bf16_rne(w);
    }
    if (t < 192) {
        int h = t >> 1;
        bc[t] = (t & 1) ? by[h] : bx[h];
    }
}

// ---------------- Lift (MFMA): tanh(x @ [Wx|Wy] + b) ----------------

#define LW_STRIDE 136

__global__ __launch_bounds__(256) void lift_mfma_kernel(
    const float* __restrict__ x, const unsigned short* __restrict__ WcT,
    const float* __restrict__ bc, float* __restrict__ XYf,
    unsigned* __restrict__ F, int N) {
    __shared__ unsigned short sW[192 * LW_STRIDE];  // 52224 B
    __shared__ float sBc[192];
    int t = threadIdx.x;

    {
        const unsigned* g = (const unsigned*)WcT;  // 192*64 uints
        unsigned* s = (unsigned*)sW;
        for (int i = t; i < 192 * 64; i += 256) {
            int cc = i >> 6;
            int kp = i & 63;
            s[cc * (LW_STRIDE / 2) + kp] = g[i];
        }
    }
    if (t < 192) sBc[t] = bc[t];
    __syncthreads();

    int wv = t >> 6;
    int lane = t & 63;
    int quad = lane >> 4;
    int m = lane & 15;
    int mbase = blockIdx.x * 64 + wv * 16;

    int anode = mbase + m;
    if (anode >= N) anode = N - 1;  // clamp; stores guarded
    const float* xrow = x + (size_t)anode * CIN;

    vfloat4 acc[12];
#pragma unroll
    for (int i = 0; i < 12; i++) acc[i] = (vfloat4){0.f, 0.f, 0.f, 0.f};

#pragma unroll
    for (int kt = 0; kt < 4; kt++) {
        int k0 = kt * 32 + quad * 8;
        float4 xa = *(const float4*)(xrow + k0);
        float4 xb = *(const float4*)(xrow + k0 + 4);
        uint4 ua;
        ua.x = pack_bf16_pair(xa.x, xa.y);
        ua.y = pack_bf16_pair(xa.z, xa.w);
        ua.z = pack_bf16_pair(xb.x, xb.y);
        ua.w = pack_bf16_pair(xb.z, xb.w);
        vshort8 a = *(vshort8*)&ua;
#pragma unroll
        for (int nt = 0; nt < 12; nt++) {
            vshort8 b = *(const vshort8*)&sW[(nt * 16 + m) * LW_STRIDE + k0];
            acc[nt] = __builtin_amdgcn_mfma_f32_16x16x32_bf16(a, b, acc[nt], 0, 0, 0);
        }
    }

    // C/D: row(node) = quad*4+reg, col(cc within tile) = lane&15
#pragma unroll
    for (int nt = 0; nt < 12; nt++) {
        int ccb = nt * 16 + m;
        float bco = sBc[ccb];
#pragma unroll
        for (int r = 0; r < 4; r++) {
            int node = mbase + quad * 4 + r;
            float v = tanhf(acc[nt][r] + bco);
            unsigned u = (unsigned)(__builtin_amdgcn_cvt_pk_fp8_f32(
                             v, __shfl_xor(v, 1), 0, false) & 0xffff);
            unsigned w = u | (((unsigned)__shfl_xor((int)u, 2)) << 16);
            if (node < N) {
                XYf[(size_t)node * 192 + ccb] = v;
                if ((m & 3) == 0) F[(size_t)node * 48 + (ccb >> 2)] = w;
            }
        }
    }
}

// ---------------- Layer: mean agg + LV Euler update ----------------

#define LWPB 4

__global__ __launch_bounds__(256) void layer_kernel(
    const unsigned* __restrict__ F, const float4* __restrict__ XY4,
    float4* __restrict__ XYn4, unsigned* __restrict__ Fn, unsigned* __restrict__ Mn,
    const int* __restrict__ rowptr, const int* __restrict__ csr,
    const float* __restrict__ deg_inv,
    const float* __restrict__ alpha, const float* __restrict__ beta,
    const float* __restrict__ gamma, const float* __restrict__ delta,
    int N) {
    int wave = threadIdx.x >> 6;
    int lane = threadIdx.x & 63;
    int node = blockIdx.x * LWPB + wave;
    if (node >= N) return;

    int beg = rowptr[node];
    int cnt = rowptr[node + 1] - beg;
    bool act = (lane < 48);

    float ax0 = 0.f, ay0 = 0.f, ax1 = 0.f, ay1 = 0.f;

#define UNPACK_ACC(u)                                                      \
    do {                                                                   \
        vfloat2 p0 = __builtin_amdgcn_cvt_pk_f32_fp8((int)(u), false);     \
        vfloat2 p1 = __builtin_amdgcn_cvt_pk_f32_fp8((int)(u), true);      \
        ax0 += p0.x; ay0 += p0.y; ax1 += p1.x; ay1 += p1.y;                \
    } while (0)

    for (int base = 0; base < cnt; base += 64) {
        int m = min(64, cnt - base);
        int sidx = (lane < m) ? csr[beg + base + lane] : 0;
        int j = 0;
        for (; j + 8 <= m; j += 8) {
            int s0 = __shfl(sidx, j);
            int s1 = __shfl(sidx, j + 1);
            int s2 = __shfl(sidx, j + 2);
            int s3 = __shfl(sidx, j + 3);
            int s4 = __shfl(sidx, j + 4);
            int s5 = __shfl(sidx, j + 5);
            int s6 = __shfl(sidx, j + 6);
            int s7 = __shfl(sidx, j + 7);
            if (act) {
                unsigned u0 = F[(size_t)s0 * 48 + lane];
                unsigned u1 = F[(size_t)s1 * 48 + lane];
                unsigned u2 = F[(size_t)s2 * 48 + lane];
                unsigned u3 = F[(size_t)s3 * 48 + lane];
                unsigned u4 = F[(size_t)s4 * 48 + lane];
                unsigned u5 = F[(size_t)s5 * 48 + lane];
                unsigned u6 = F[(size_t)s6 * 48 + lane];
                unsigned u7 = F[(size_t)s7 * 48 + lane];
                UNPACK_ACC(u0); UNPACK_ACC(u1); UNPACK_ACC(u2); UNPACK_ACC(u3);
                UNPACK_ACC(u4); UNPACK_ACC(u5); UNPACK_ACC(u6); UNPACK_ACC(u7);
            }
        }
        for (; j < m; j++) {
            int s = __shfl(sidx, j);
            if (act) {
                unsigned u = F[(size_t)s * 48 + lane];
                UNPACK_ACC(u);
            }
        }
    }
#undef UNPACK_ACC

    float dinv = deg_inv[node];
    if (act) {
        ax0 *= dinv; ay0 *= dinv; ax1 *= dinv; ay1 *= dinv;
        float2 a2 = ((const float2*)alpha)[lane];
        float2 b2 = ((const float2*)beta)[lane];
        float2 g2 = ((const float2*)gamma)[lane];
        float2 d2 = ((const float2*)delta)[lane];
        float4 v = XY4[(size_t)node * 48 + lane];
        float4 o;
        o.x = v.x + DTC * v.x * (a2.x - b2.x * ay0);
        o.y = v.y + DTC * v.y * (-g2.x + d2.x * ax0);
        o.z = v.z + DTC * v.z * (a2.y - b2.y * ay1);
        o.w = v.w + DTC * v.w * (-g2.y + d2.y * ax1);
        XYn4[(size_t)node * 48 + lane] = o;
        if (Fn)
            Fn[(size_t)node * 48 + lane] = pack_fp8_quad(o.x, o.y, o.z, o.w);
        if (Mn)
            ((uint2*)(Mn + (size_t)node * HDIM))[lane] =
                make_uint2(pack_bf16_pair(o.x, o.y), pack_bf16_pair(o.z, o.w));
    }
}

// ---------------- Readout: out = [X,Y] @ Wr + br via MFMA ----------------

#define WG_STRIDE 200

__global__ __launch_bounds__(256) void readout_mfma_kernel(
    const unsigned short* __restrict__ mb, const float* __restrict__ Wr,
    const float* __restrict__ br, float* __restrict__ out, int N) {
    __shared__ unsigned short sW[48 * WG_STRIDE];
    __shared__ float sB[48];
    int t = threadIdx.x;

    for (int i = t; i < 48 * 192; i += 256) {
        int n = i / 192;
        int kk = i - n * 192;
        int h = kk >> 1;
        float w = 0.f;
        if (n < COUT) w = (kk & 1) ? Wr[(HDIM + h) * COUT + n] : Wr[h * COUT + n];
        sW[n * WG_STRIDE + kk] = (unsigned short)bf16_rne(w);
    }
    if (t < 48) sB[t] = (t < COUT) ? br[t] : 0.f;
    __syncthreads();

    int wv = t >> 6;
    int lane = t & 63;
    int quad = lane >> 4;
    int m = lane & 15;
    int mbase = blockIdx.x * 64 + wv * 16;

    int anode = mbase + m;
    if (anode >= N) anode = N - 1;
    const unsigned short* arow = mb + (size_t)anode * 192;

    vfloat4 acc0 = {0.f, 0.f, 0.f, 0.f};
    vfloat4 acc1 = {0.f, 0.f, 0.f, 0.f};
    vfloat4 acc2 = {0.f, 0.f, 0.f, 0.f};

#pragma unroll
    for (int kt = 0; kt < 6; kt++) {
        int k0 = kt * 32 + quad * 8;
        vshort8 a = *(const vshort8*)(arow + k0);
        vshort8 b0 = *(const vshort8*)&sW[(0 * 16 + m) * WG_STRIDE + k0];
        vshort8 b1 = *(const vshort8*)&sW[(1 * 16 + m) * WG_STRIDE + k0];
        vshort8 b2 = *(const vshort8*)&sW[(2 * 16 + m) * WG_STRIDE + k0];
        acc0 = __builtin_amdgcn_mfma_f32_16x16x32_bf16(a, b0, acc0, 0, 0, 0);
        acc1 = __builtin_amdgcn_mfma_f32_16x16x32_bf16(a, b1, acc1, 0, 0, 0);
        acc2 = __builtin_amdgcn_mfma_f32_16x16x32_bf16(a, b2, acc2, 0, 0, 0);
    }

    float bo0 = sB[m];
    float bo1 = sB[16 + m];
    float bo2 = (m < 8) ? sB[32 + m] : 0.f;
#pragma unroll
    for (int r = 0; r < 4; r++) {
        int node = mbase + quad * 4 + r;
        if (node < N) {
            float* orow = out + (size_t)node * COUT;
            orow[m] = acc0[r] + bo0;
            orow[16 + m] = acc1[r] + bo1;
            if (m < 8) orow[32 + m] = acc2[r] + bo2;
        }
    }
}

// ---------------- launch ----------------

extern "C" void kernel_launch(void* const* d_in, const int* in_sizes, int n_in,
                              void* d_out, int out_size, void* d_ws, size_t ws_size,
                              hipStream_t stream) {
    const float* x     = (const float*)d_in[0];
    const int*   ei    = (const int*)d_in[1];
    const float* Wx    = (const float*)d_in[2];
    const float* bx    = (const float*)d_in[3];
    const float* Wy    = (const float*)d_in[4];
    const float* by    = (const float*)d_in[5];
    const float* alpha = (const float*)d_in[6];
    const float* beta  = (const float*)d_in[7];
    const float* gamma = (const float*)d_in[8];
    const float* delta = (const float*)d_in[9];
    const float* Wr    = (const float*)d_in[10];
    const float* br    = (const float*)d_in[11];

    const int N = in_sizes[0] / CIN;
    const int E = in_sizes[1] / 2;
    const int NB = (N + BK_SIZE - 1) >> BK_SHIFT;     // 391 for N=50000 (<=512)
    const int nchunk = (E + EPB - 1) / EPB;           // 196 for E=800000

    char* ws = (char*)d_ws;
    size_t off = 0;
    auto alloc = [&](size_t bytes) -> void* {
        off = (off + 255) & ~(size_t)255;
        void* p = ws + off;
        off += bytes;
        return p;
    };
    int* ghist     = (int*)alloc((size_t)NB * sizeof(int));
    int* bbase     = (int*)alloc((size_t)(NB + 1) * sizeof(int));
    int* bcursor   = (int*)alloc((size_t)NB * sizeof(int));
    unsigned* pckd = (unsigned*)alloc((size_t)E * sizeof(unsigned));
    int* rowptr    = (int*)alloc((size_t)(N + 1) * sizeof(int));
    int* csr       = (int*)alloc((size_t)E * sizeof(int));
    float* dinv    = (float*)alloc((size_t)N * sizeof(float));
    float* XYa     = (float*)alloc((size_t)N * 192 * sizeof(float));
    float* XYb     = (float*)alloc((size_t)N * 192 * sizeof(float));
    unsigned* Fa   = (unsigned*)alloc((size_t)N * 48 * sizeof(unsigned));   // fp8 mirror
    unsigned* Fb   = (unsigned*)alloc((size_t)N * 48 * sizeof(unsigned));
    unsigned* Mb16 = (unsigned*)alloc((size_t)N * HDIM * sizeof(unsigned)); // bf16 mirror
    unsigned short* WcT = (unsigned short*)alloc((size_t)192 * 128 * sizeof(unsigned short));
    float* bc      = (float*)alloc((size_t)192 * sizeof(float));
    (void)ws_size;

    const int* e_src = ei;
    const int* e_dst = ei + E;

    hipMemsetAsync(ghist, 0, (size_t)NB * sizeof(int), stream);

    bhist_kernel<<<nchunk, 256, 0, stream>>>(e_dst, ghist, E, NB);
    bscan_kernel<<<1, 512, 0, stream>>>(ghist, bbase, bcursor, rowptr, NB, N, E);
    bscatter_kernel<<<nchunk, 256, 0, stream>>>(e_src, e_dst, bcursor, pckd, E, NB);
    bcsr_kernel<<<NB, 256, 0, stream>>>(pckd, bbase, rowptr, dinv, csr, N, NB);

    wprep_kernel<<<(192 * 128 + 255) / 256, 256, 0, stream>>>(Wx, bx, Wy, by, WcT, bc);
    lift_mfma_kernel<<<(N + 63) / 64, 256, 0, stream>>>(x, WcT, bc, XYa, Fa, N);

    const float* XYc = XYa;
    float* XYn = XYb;
    const unsigned* Fc = Fa;
    unsigned* Fnx = Fb;
    for (int l = 0; l < NLAYER; l++) {
        bool last = (l == NLAYER - 1);
        layer_kernel<<<(N + LWPB - 1) / LWPB, LWPB * 64, 0, stream>>>(
            Fc, (const float4*)XYc, (float4*)XYn,
            last ? (unsigned*)nullptr : Fnx,
            last ? Mb16 : (unsigned*)nullptr,
            rowptr, csr, dinv,
            alpha + l * HDIM, beta + l * HDIM, gamma + l * HDIM, delta + l * HDIM, N);
        const float* t2 = XYc; XYc = XYn; XYn = (float*)t2;
        const unsigned* tf = Fc; Fc = Fnx; Fnx = (unsigned*)tf;
    }

    readout_mfma_kernel<<<(N + 63) / 64, 256, 0, stream>>>(
        (const unsigned short*)Mb16, Wr, br, (float*)d_out, N);
}

// Round 8
// 354.685 us; speedup vs baseline: 3.0183x; 1.0380x over previous
//
#include <hip/hip_runtime.h>
#include <hip/hip_bf16.h>
#include <hip/hip_fp16.h>

// PPGNN: lift -> 5x (mean-aggregate + Lotka-Volterra Euler step) -> readout
// N=50000, E=800000, C_IN=128, H=96, C_OUT=40, L=5, DT=0.05
//
// Master state S: fp16, row = 192 halfs = 96 uints (cc even = X[cc/2], odd
// = Y[cc/2]). fp16 rounding per layer ~2.4e-4 relative -- negligible vs the
// fp8-gather term. fp8 e4m3 mirror F (uint = 4 fp8 for 2 channel pairs; row
// 192 B) is what layer gathers read. Readout consumes the final fp16 state
// directly via f16 MFMA (no separate bf16 mirror). Lift + readout are MFMA
// GEMMs; CSR build is the bucketed atomic-light build.

#define HDIM 96
#define CIN 128
#define COUT 40
#define NLAYER 5
#define DTC 0.05f

#define BK_SHIFT 7
#define BK_SIZE 128
#define EPB 4096   // edges per block in bucket hist/scatter

typedef float  vfloat2 __attribute__((ext_vector_type(2)));
typedef float  vfloat4 __attribute__((ext_vector_type(4)));
typedef short  vshort8 __attribute__((ext_vector_type(8)));

__device__ __forceinline__ unsigned bf16_rne(float f) {
    unsigned u = __float_as_uint(f);
    return (u + 0x7fffu + ((u >> 16) & 1u)) >> 16;
}

__device__ __forceinline__ unsigned pack_bf16_pair(float xf, float yf) {
    return bf16_rne(xf) | (bf16_rne(yf) << 16);
}

__device__ __forceinline__ unsigned pack_f16_pair(float a, float b) {
    unsigned ha = (unsigned)__half_as_ushort(__float2half_rn(a));
    unsigned hb = (unsigned)__half_as_ushort(__float2half_rn(b));
    return ha | (hb << 16);
}

__device__ __forceinline__ float f16_lo(unsigned u) {
    return __half2float(__ushort_as_half((unsigned short)(u & 0xffffu)));
}
__device__ __forceinline__ float f16_hi(unsigned u) {
    return __half2float(__ushort_as_half((unsigned short)(u >> 16)));
}

__device__ __forceinline__ unsigned pack_fp8_quad(float x0, float y0, float x1, float y1) {
    int lo = __builtin_amdgcn_cvt_pk_fp8_f32(x0, y0, 0, false);
    int full = __builtin_amdgcn_cvt_pk_fp8_f32(x1, y1, lo, true);
    return (unsigned)full;
}

// ---------------- CSR build (bucketed, atomic-light) ----------------

__global__ __launch_bounds__(256) void bhist_kernel(const int* __restrict__ dst,
                                                    int* __restrict__ ghist, int E, int NB) {
    __shared__ int h[512];
    for (int i = threadIdx.x; i < NB; i += 256) h[i] = 0;
    __syncthreads();
    int base = blockIdx.x * EPB;
    int end = min(E, base + EPB);
    for (int e = base + threadIdx.x; e < end; e += 256)
        atomicAdd(&h[dst[e] >> BK_SHIFT], 1);
    __syncthreads();
    for (int i = threadIdx.x; i < NB; i += 256)
        if (h[i]) atomicAdd(&ghist[i], h[i]);
}

__global__ void bscan_kernel(const int* __restrict__ ghist, int* __restrict__ bbase,
                             int* __restrict__ bcursor, int* __restrict__ rowptr,
                             int NB, int N, int E) {
    __shared__ int sd[512];
    int t = threadIdx.x;
    int v = (t < NB) ? ghist[t] : 0;
    sd[t] = v;
    __syncthreads();
    for (int off = 1; off < 512; off <<= 1) {
        int tv = (t >= off) ? sd[t - off] : 0;
        __syncthreads();
        sd[t] += tv;
        __syncthreads();
    }
    if (t < NB) {
        int b = sd[t] - v;  // exclusive
        bbase[t] = b;
        bcursor[t] = b;
    }
    if (t == 0) { bbase[NB] = E; rowptr[N] = E; }
}

__global__ __launch_bounds__(256) void bscatter_kernel(
    const int* __restrict__ src, const int* __restrict__ dst,
    int* __restrict__ bcursor, unsigned* __restrict__ packed, int E, int NB) {
    __shared__ int h[512];
    __shared__ int cur[512];
    for (int i = threadIdx.x; i < NB; i += 256) h[i] = 0;
    __syncthreads();
    int base = blockIdx.x * EPB;
    int end = min(E, base + EPB);
    for (int e = base + threadIdx.x; e < end; e += 256)
        atomicAdd(&h[dst[e] >> BK_SHIFT], 1);
    __syncthreads();
    for (int i = threadIdx.x; i < NB; i += 256)
        cur[i] = h[i] ? atomicAdd(&bcursor[i], h[i]) : 0;
    __syncthreads();
    for (int e = base + threadIdx.x; e < end; e += 256) {
        int d = dst[e];
        int b = d >> BK_SHIFT;
        int pos = atomicAdd(&cur[b], 1);
        packed[pos] = (unsigned)src[e] | ((unsigned)(d & (BK_SIZE - 1)) << 17);
    }
}

__global__ __launch_bounds__(256) void bcsr_kernel(
    const unsigned* __restrict__ packed, const int* __restrict__ bbase,
    int* __restrict__ rowptr, float* __restrict__ dinv, int* __restrict__ csr,
    int N, int NB) {
    __shared__ int ldeg[BK_SIZE];
    __shared__ int sscan[BK_SIZE];
    __shared__ int lcur[BK_SIZE];
    int b = blockIdx.x;
    int t = threadIdx.x;
    int lo = bbase[b], hi = bbase[b + 1];
    if (t < BK_SIZE) ldeg[t] = 0;
    __syncthreads();
    for (int e = lo + t; e < hi; e += 256)
        atomicAdd(&ldeg[(packed[e] >> 17) & (BK_SIZE - 1)], 1);
    __syncthreads();
    if (t < BK_SIZE) sscan[t] = ldeg[t];
    __syncthreads();
    for (int off = 1; off < BK_SIZE; off <<= 1) {
        int tv = (t < BK_SIZE && t >= off) ? sscan[t - off] : 0;
        __syncthreads();
        if (t < BK_SIZE) sscan[t] += tv;
        __syncthreads();
    }
    if (t < BK_SIZE) {
        int excl = sscan[t] - ldeg[t];
        int gpos = lo + excl;
        lcur[t] = gpos;
        int node = b * BK_SIZE + t;
        if (node < N) {
            rowptr[node] = gpos;
            dinv[node] = 1.0f / fmaxf((float)ldeg[t], 1.0f);
        }
    }
    __syncthreads();
    for (int e = lo + t; e < hi; e += 256) {
        unsigned p = packed[e];
        int l = (p >> 17) & (BK_SIZE - 1);
        int pos = atomicAdd(&lcur[l], 1);
        csr[pos] = (int)(p & 0x1FFFFu);
    }
}

// ---------------- Weight prep: Wx,Wy fp32 -> interleaved bf16 WcT + bias ----

__global__ __launch_bounds__(256) void wprep_kernel(
    const float* __restrict__ Wx, const float* __restrict__ bx,
    const float* __restrict__ Wy, const float* __restrict__ by,
    unsigned short* __restrict__ WcT, float* __restrict__ bc) {
    int t = blockIdx.x * blockDim.x + threadIdx.x;
    if (t < 192 * 128) {
        int cc = t >> 7;
        int k = t & 127;
        int h = cc >> 1;
        float w = (cc & 1) ? Wy[k * HDIM + h] : Wx[k * HDIM + h];
        WcT[cc * 128 + k] = (unsigned short)bf16_rne(w);
    }
    if (t < 192) {
        int h = t >> 1;
        bc[t] = (t & 1) ? by[h] : bx[h];
    }
}

// ---------------- Lift (MFMA): tanh(x @ [Wx|Wy] + b) ----------------
// Epilogue: +bias, tanh, fp16 state store (even-m lanes, dword) + fp8 quad
// pack via shfl_xor ((m&3)==0 lanes).

#define LW_STRIDE 136

__global__ __launch_bounds__(256) void lift_mfma_kernel(
    const float* __restrict__ x, const unsigned short* __restrict__ WcT,
    const float* __restrict__ bc, unsigned* __restrict__ S,
    unsigned* __restrict__ F, int N) {
    __shared__ unsigned short sW[192 * LW_STRIDE];  // 52224 B
    __shared__ float sBc[192];
    int t = threadIdx.x;

    {
        const unsigned* g = (const unsigned*)WcT;  // 192*64 uints
        unsigned* s = (unsigned*)sW;
        for (int i = t; i < 192 * 64; i += 256) {
            int cc = i >> 6;
            int kp = i & 63;
            s[cc * (LW_STRIDE / 2) + kp] = g[i];
        }
    }
    if (t < 192) sBc[t] = bc[t];
    __syncthreads();

    int wv = t >> 6;
    int lane = t & 63;
    int quad = lane >> 4;
    int m = lane & 15;
    int mbase = blockIdx.x * 64 + wv * 16;

    int anode = mbase + m;
    if (anode >= N) anode = N - 1;  // clamp; stores guarded
    const float* xrow = x + (size_t)anode * CIN;

    vfloat4 acc[12];
#pragma unroll
    for (int i = 0; i < 12; i++) acc[i] = (vfloat4){0.f, 0.f, 0.f, 0.f};

#pragma unroll
    for (int kt = 0; kt < 4; kt++) {
        int k0 = kt * 32 + quad * 8;
        float4 xa = *(const float4*)(xrow + k0);
        float4 xb = *(const float4*)(xrow + k0 + 4);
        uint4 ua;
        ua.x = pack_bf16_pair(xa.x, xa.y);
        ua.y = pack_bf16_pair(xa.z, xa.w);
        ua.z = pack_bf16_pair(xb.x, xb.y);
        ua.w = pack_bf16_pair(xb.z, xb.w);
        vshort8 a = *(vshort8*)&ua;
#pragma unroll
        for (int nt = 0; nt < 12; nt++) {
            vshort8 b = *(const vshort8*)&sW[(nt * 16 + m) * LW_STRIDE + k0];
            acc[nt] = __builtin_amdgcn_mfma_f32_16x16x32_bf16(a, b, acc[nt], 0, 0, 0);
        }
    }

    // C/D: row(node) = quad*4+reg, col(cc within tile) = lane&15
#pragma unroll
    for (int nt = 0; nt < 12; nt++) {
        int ccb = nt * 16 + m;
        float bco = sBc[ccb];
#pragma unroll
        for (int r = 0; r < 4; r++) {
            int node = mbase + quad * 4 + r;
            float v = tanhf(acc[nt][r] + bco);
            float v1 = __shfl_xor(v, 1);  // partner channel (m^1)
            unsigned u = (unsigned)(__builtin_amdgcn_cvt_pk_fp8_f32(v, v1, 0, false) & 0xffff);
            unsigned w = u | (((unsigned)__shfl_xor((int)u, 2)) << 16);
            unsigned hp = pack_f16_pair(v, v1);
            if (node < N) {
                if ((m & 1) == 0) S[(size_t)node * 96 + (ccb >> 1)] = hp;
                if ((m & 3) == 0) F[(size_t)node * 48 + (ccb >> 2)] = w;
            }
        }
    }
}

// ---------------- Layer: mean agg + LV Euler update ----------------
// One wave per node. CSR indices preloaded 64-wide, broadcast via __shfl.
// Gathers read the fp8 mirror (one dword / 192 B per row). 8-edge unroll.
// Update reads own fp16 state row (uint2/lane), writes fp16 next + fp8
// mirror (skipped on last layer; readout reads the fp16 state directly).

#define LWPB 4

__global__ __launch_bounds__(256) void layer_kernel(
    const unsigned* __restrict__ F, const unsigned* __restrict__ S,
    unsigned* __restrict__ Sn, unsigned* __restrict__ Fn,
    const int* __restrict__ rowptr, const int* __restrict__ csr,
    const float* __restrict__ deg_inv,
    const float* __restrict__ alpha, const float* __restrict__ beta,
    const float* __restrict__ gamma, const float* __restrict__ delta,
    int N) {
    int wave = threadIdx.x >> 6;
    int lane = threadIdx.x & 63;
    int node = blockIdx.x * LWPB + wave;
    if (node >= N) return;

    int beg = rowptr[node];
    int cnt = rowptr[node + 1] - beg;
    bool act = (lane < 48);

    float ax0 = 0.f, ay0 = 0.f, ax1 = 0.f, ay1 = 0.f;

#define UNPACK_ACC(u)                                                      \
    do {                                                                   \
        vfloat2 p0 = __builtin_amdgcn_cvt_pk_f32_fp8((int)(u), false);     \
        vfloat2 p1 = __builtin_amdgcn_cvt_pk_f32_fp8((int)(u), true);      \
        ax0 += p0.x; ay0 += p0.y; ax1 += p1.x; ay1 += p1.y;                \
    } while (0)

    for (int base = 0; base < cnt; base += 64) {
        int m = min(64, cnt - base);
        int sidx = (lane < m) ? csr[beg + base + lane] : 0;
        int j = 0;
        for (; j + 8 <= m; j += 8) {
            int s0 = __shfl(sidx, j);
            int s1 = __shfl(sidx, j + 1);
            int s2 = __shfl(sidx, j + 2);
            int s3 = __shfl(sidx, j + 3);
            int s4 = __shfl(sidx, j + 4);
            int s5 = __shfl(sidx, j + 5);
            int s6 = __shfl(sidx, j + 6);
            int s7 = __shfl(sidx, j + 7);
            if (act) {
                unsigned u0 = F[(size_t)s0 * 48 + lane];
                unsigned u1 = F[(size_t)s1 * 48 + lane];
                unsigned u2 = F[(size_t)s2 * 48 + lane];
                unsigned u3 = F[(size_t)s3 * 48 + lane];
                unsigned u4 = F[(size_t)s4 * 48 + lane];
                unsigned u5 = F[(size_t)s5 * 48 + lane];
                unsigned u6 = F[(size_t)s6 * 48 + lane];
                unsigned u7 = F[(size_t)s7 * 48 + lane];
                UNPACK_ACC(u0); UNPACK_ACC(u1); UNPACK_ACC(u2); UNPACK_ACC(u3);
                UNPACK_ACC(u4); UNPACK_ACC(u5); UNPACK_ACC(u6); UNPACK_ACC(u7);
            }
        }
        for (; j < m; j++) {
            int s = __shfl(sidx, j);
            if (act) {
                unsigned u = F[(size_t)s * 48 + lane];
                UNPACK_ACC(u);
            }
        }
    }
#undef UNPACK_ACC

    float dinv = deg_inv[node];
    if (act) {
        ax0 *= dinv; ay0 *= dinv; ax1 *= dinv; ay1 *= dinv;
        float2 a2 = ((const float2*)alpha)[lane];
        float2 b2 = ((const float2*)beta)[lane];
        float2 g2 = ((const float2*)gamma)[lane];
        float2 d2 = ((const float2*)delta)[lane];
        uint2 su = ((const uint2*)(S + (size_t)node * 96))[lane];
        float vx = f16_lo(su.x), vy = f16_hi(su.x);
        float vz = f16_lo(su.y), vw = f16_hi(su.y);
        float ox = vx + DTC * vx * (a2.x - b2.x * ay0);
        float oy = vy + DTC * vy * (-g2.x + d2.x * ax0);
        float oz = vz + DTC * vz * (a2.y - b2.y * ay1);
        float ow = vw + DTC * vw * (-g2.y + d2.y * ax1);
        ((uint2*)(Sn + (size_t)node * 96))[lane] =
            make_uint2(pack_f16_pair(ox, oy), pack_f16_pair(oz, ow));
        if (Fn)
            Fn[(size_t)node * 48 + lane] = pack_fp8_quad(ox, oy, oz, ow);
    }
}

// ---------------- Readout: out = [X,Y] @ Wr + br via f16 MFMA ----------------
// A = final fp16 state rows (k interleaved: k=2h -> X[h], k=2h+1 -> Y[h]).

#define WG_STRIDE 200

__global__ __launch_bounds__(256) void readout_mfma_kernel(
    const unsigned short* __restrict__ sh, const float* __restrict__ Wr,
    const float* __restrict__ br, float* __restrict__ out, int N) {
    __shared__ unsigned short sW[48 * WG_STRIDE];
    __shared__ float sB[48];
    int t = threadIdx.x;

    for (int i = t; i < 48 * 192; i += 256) {
        int n = i / 192;
        int kk = i - n * 192;
        int h = kk >> 1;
        float w = 0.f;
        if (n < COUT) w = (kk & 1) ? Wr[(HDIM + h) * COUT + n] : Wr[h * COUT + n];
        sW[n * WG_STRIDE + kk] = __half_as_ushort(__float2half_rn(w));
    }
    if (t < 48) sB[t] = (t < COUT) ? br[t] : 0.f;
    __syncthreads();

    int wv = t >> 6;
    int lane = t & 63;
    int quad = lane >> 4;
    int m = lane & 15;
    int mbase = blockIdx.x * 64 + wv * 16;

    int anode = mbase + m;
    if (anode >= N) anode = N - 1;
    const unsigned short* arow = sh + (size_t)anode * 192;

    vfloat4 acc0 = {0.f, 0.f, 0.f, 0.f};
    vfloat4 acc1 = {0.f, 0.f, 0.f, 0.f};
    vfloat4 acc2 = {0.f, 0.f, 0.f, 0.f};

#pragma unroll
    for (int kt = 0; kt < 6; kt++) {
        int k0 = kt * 32 + quad * 8;
        vshort8 a = *(const vshort8*)(arow + k0);
        vshort8 b0 = *(const vshort8*)&sW[(0 * 16 + m) * WG_STRIDE + k0];
        vshort8 b1 = *(const vshort8*)&sW[(1 * 16 + m) * WG_STRIDE + k0];
        vshort8 b2 = *(const vshort8*)&sW[(2 * 16 + m) * WG_STRIDE + k0];
        acc0 = __builtin_amdgcn_mfma_f32_16x16x32_f16(a, b0, acc0, 0, 0, 0);
        acc1 = __builtin_amdgcn_mfma_f32_16x16x32_f16(a, b1, acc1, 0, 0, 0);
        acc2 = __builtin_amdgcn_mfma_f32_16x16x32_f16(a, b2, acc2, 0, 0, 0);
    }

    float bo0 = sB[m];
    float bo1 = sB[16 + m];
    float bo2 = (m < 8) ? sB[32 + m] : 0.f;
#pragma unroll
    for (int r = 0; r < 4; r++) {
        int node = mbase + quad * 4 + r;
        if (node < N) {
            float* orow = out + (size_t)node * COUT;
            orow[m] = acc0[r] + bo0;
            orow[16 + m] = acc1[r] + bo1;
            if (m < 8) orow[32 + m] = acc2[r] + bo2;
        }
    }
}

// ---------------- launch ----------------

extern "C" void kernel_launch(void* const* d_in, const int* in_sizes, int n_in,
                              void* d_out, int out_size, void* d_ws, size_t ws_size,
                              hipStream_t stream) {
    const float* x     = (const float*)d_in[0];
    const int*   ei    = (const int*)d_in[1];
    const float* Wx    = (const float*)d_in[2];
    const float* bx    = (const float*)d_in[3];
    const float* Wy    = (const float*)d_in[4];
    const float* by    = (const float*)d_in[5];
    const float* alpha = (const float*)d_in[6];
    const float* beta  = (const float*)d_in[7];
    const float* gamma = (const float*)d_in[8];
    const float* delta = (const float*)d_in[9];
    const float* Wr    = (const float*)d_in[10];
    const float* br    = (const float*)d_in[11];

    const int N = in_sizes[0] / CIN;
    const int E = in_sizes[1] / 2;
    const int NB = (N + BK_SIZE - 1) >> BK_SHIFT;     // 391 for N=50000 (<=512)
    const int nchunk = (E + EPB - 1) / EPB;           // 196 for E=800000

    char* ws = (char*)d_ws;
    size_t off = 0;
    auto alloc = [&](size_t bytes) -> void* {
        off = (off + 255) & ~(size_t)255;
        void* p = ws + off;
        off += bytes;
        return p;
    };
    int* ghist     = (int*)alloc((size_t)NB * sizeof(int));
    int* bbase     = (int*)alloc((size_t)(NB + 1) * sizeof(int));
    int* bcursor   = (int*)alloc((size_t)NB * sizeof(int));
    unsigned* pckd = (unsigned*)alloc((size_t)E * sizeof(unsigned));
    int* rowptr    = (int*)alloc((size_t)(N + 1) * sizeof(int));
    int* csr       = (int*)alloc((size_t)E * sizeof(int));
    float* dinv    = (float*)alloc((size_t)N * sizeof(float));
    unsigned* Sa   = (unsigned*)alloc((size_t)N * 96 * sizeof(unsigned));   // fp16 state
    unsigned* Sb   = (unsigned*)alloc((size_t)N * 96 * sizeof(unsigned));
    unsigned* Fa   = (unsigned*)alloc((size_t)N * 48 * sizeof(unsigned));   // fp8 mirror
    unsigned* Fb   = (unsigned*)alloc((size_t)N * 48 * sizeof(unsigned));
    unsigned short* WcT = (unsigned short*)alloc((size_t)192 * 128 * sizeof(unsigned short));
    float* bc      = (float*)alloc((size_t)192 * sizeof(float));
    (void)ws_size;

    const int* e_src = ei;
    const int* e_dst = ei + E;

    hipMemsetAsync(ghist, 0, (size_t)NB * sizeof(int), stream);

    bhist_kernel<<<nchunk, 256, 0, stream>>>(e_dst, ghist, E, NB);
    bscan_kernel<<<1, 512, 0, stream>>>(ghist, bbase, bcursor, rowptr, NB, N, E);
    bscatter_kernel<<<nchunk, 256, 0, stream>>>(e_src, e_dst, bcursor, pckd, E, NB);
    bcsr_kernel<<<NB, 256, 0, stream>>>(pckd, bbase, rowptr, dinv, csr, N, NB);

    wprep_kernel<<<(192 * 128 + 255) / 256, 256, 0, stream>>>(Wx, bx, Wy, by, WcT, bc);
    lift_mfma_kernel<<<(N + 63) / 64, 256, 0, stream>>>(x, WcT, bc, Sa, Fa, N);

    const unsigned* Sc = Sa;
    unsigned* Snx = Sb;
    const unsigned* Fc = Fa;
    unsigned* Fnx = Fb;
    for (int l = 0; l < NLAYER; l++) {
        bool last = (l == NLAYER - 1);
        layer_kernel<<<(N + LWPB - 1) / LWPB, LWPB * 64, 0, stream>>>(
            Fc, Sc, Snx, last ? (unsigned*)nullptr : Fnx,
            rowptr, csr, dinv,
            alpha + l * HDIM, beta + l * HDIM, gamma + l * HDIM, delta + l * HDIM, N);
        const unsigned* ts = Sc; Sc = Snx; Snx = (unsigned*)ts;
        const unsigned* tf = Fc; Fc = Fnx; Fnx = (unsigned*)tf;
    }

    readout_mfma_kernel<<<(N + 63) / 64, 256, 0, stream>>>(
        (const unsigned short*)Sc, Wr, br, (float*)d_out, N);
}

// Round 9
// 323.892 us; speedup vs baseline: 3.3053x; 1.0951x over previous
//
#include <hip/hip_runtime.h>
#include <hip/hip_bf16.h>
#include <hip/hip_fp16.h>

// PPGNN: lift -> 5x (mean-aggregate + Lotka-Volterra Euler step) -> readout
// N=50000, E=800000, C_IN=128, H=96, C_OUT=40, L=5, DT=0.05
//
// Master state S: fp16, row = 192 halfs = 96 uints (cc even = X[cc/2], odd
// = Y[cc/2]). fp8 e4m3 mirror F (uint = 4 fp8 for channel pair {2l,2l+1};
// row 48 uints = 192 B) is what layer gathers read. Readout consumes the
// final fp16 state directly via f16 MFMA. Lift + readout are MFMA GEMMs;
// CSR build is the bucketed atomic-light build.
// Layer kernel: 4 nodes per wave (16 lanes/node, dwordx3 row fragments) --
// full lane utilization, 4 gathered rows per wave instruction.

#define HDIM 96
#define CIN 128
#define COUT 40
#define NLAYER 5
#define DTC 0.05f

#define BK_SHIFT 7
#define BK_SIZE 128
#define EPB 4096   // edges per block in bucket hist/scatter

typedef float  vfloat2 __attribute__((ext_vector_type(2)));
typedef float  vfloat4 __attribute__((ext_vector_type(4)));
typedef short  vshort8 __attribute__((ext_vector_type(8)));

__device__ __forceinline__ unsigned bf16_rne(float f) {
    unsigned u = __float_as_uint(f);
    return (u + 0x7fffu + ((u >> 16) & 1u)) >> 16;
}

__device__ __forceinline__ unsigned pack_bf16_pair(float xf, float yf) {
    return bf16_rne(xf) | (bf16_rne(yf) << 16);
}

__device__ __forceinline__ unsigned pack_f16_pair(float a, float b) {
    unsigned ha = (unsigned)__half_as_ushort(__float2half_rn(a));
    unsigned hb = (unsigned)__half_as_ushort(__float2half_rn(b));
    return ha | (hb << 16);
}

__device__ __forceinline__ float f16_lo(unsigned u) {
    return __half2float(__ushort_as_half((unsigned short)(u & 0xffffu)));
}
__device__ __forceinline__ float f16_hi(unsigned u) {
    return __half2float(__ushort_as_half((unsigned short)(u >> 16)));
}

__device__ __forceinline__ unsigned pack_fp8_quad(float x0, float y0, float x1, float y1) {
    int lo = __builtin_amdgcn_cvt_pk_fp8_f32(x0, y0, 0, false);
    int full = __builtin_amdgcn_cvt_pk_fp8_f32(x1, y1, lo, true);
    return (unsigned)full;
}

// ---------------- CSR build (bucketed, atomic-light) ----------------

__global__ __launch_bounds__(256) void bhist_kernel(const int* __restrict__ dst,
                                                    int* __restrict__ ghist, int E, int NB) {
    __shared__ int h[512];
    for (int i = threadIdx.x; i < NB; i += 256) h[i] = 0;
    __syncthreads();
    int base = blockIdx.x * EPB;
    int end = min(E, base + EPB);
    for (int e = base + threadIdx.x; e < end; e += 256)
        atomicAdd(&h[dst[e] >> BK_SHIFT], 1);
    __syncthreads();
    for (int i = threadIdx.x; i < NB; i += 256)
        if (h[i]) atomicAdd(&ghist[i], h[i]);
}

__global__ void bscan_kernel(const int* __restrict__ ghist, int* __restrict__ bbase,
                             int* __restrict__ bcursor, int* __restrict__ rowptr,
                             int NB, int N, int E) {
    __shared__ int sd[512];
    int t = threadIdx.x;
    int v = (t < NB) ? ghist[t] : 0;
    sd[t] = v;
    __syncthreads();
    for (int off = 1; off < 512; off <<= 1) {
        int tv = (t >= off) ? sd[t - off] : 0;
        __syncthreads();
        sd[t] += tv;
        __syncthreads();
    }
    if (t < NB) {
        int b = sd[t] - v;  // exclusive
        bbase[t] = b;
        bcursor[t] = b;
    }
    if (t == 0) { bbase[NB] = E; rowptr[N] = E; }
}

__global__ __launch_bounds__(256) void bscatter_kernel(
    const int* __restrict__ src, const int* __restrict__ dst,
    int* __restrict__ bcursor, unsigned* __restrict__ packed, int E, int NB) {
    __shared__ int h[512];
    __shared__ int cur[512];
    for (int i = threadIdx.x; i < NB; i += 256) h[i] = 0;
    __syncthreads();
    int base = blockIdx.x * EPB;
    int end = min(E, base + EPB);
    for (int e = base + threadIdx.x; e < end; e += 256)
        atomicAdd(&h[dst[e] >> BK_SHIFT], 1);
    __syncthreads();
    for (int i = threadIdx.x; i < NB; i += 256)
        cur[i] = h[i] ? atomicAdd(&bcursor[i], h[i]) : 0;
    __syncthreads();
    for (int e = base + threadIdx.x; e < end; e += 256) {
        int d = dst[e];
        int b = d >> BK_SHIFT;
        int pos = atomicAdd(&cur[b], 1);
        packed[pos] = (unsigned)src[e] | ((unsigned)(d & (BK_SIZE - 1)) << 17);
    }
}

__global__ __launch_bounds__(256) void bcsr_kernel(
    const unsigned* __restrict__ packed, const int* __restrict__ bbase,
    int* __restrict__ rowptr, float* __restrict__ dinv, int* __restrict__ csr,
    int N, int NB) {
    __shared__ int ldeg[BK_SIZE];
    __shared__ int sscan[BK_SIZE];
    __shared__ int lcur[BK_SIZE];
    int b = blockIdx.x;
    int t = threadIdx.x;
    int lo = bbase[b], hi = bbase[b + 1];
    if (t < BK_SIZE) ldeg[t] = 0;
    __syncthreads();
    for (int e = lo + t; e < hi; e += 256)
        atomicAdd(&ldeg[(packed[e] >> 17) & (BK_SIZE - 1)], 1);
    __syncthreads();
    if (t < BK_SIZE) sscan[t] = ldeg[t];
    __syncthreads();
    for (int off = 1; off < BK_SIZE; off <<= 1) {
        int tv = (t < BK_SIZE && t >= off) ? sscan[t - off] : 0;
        __syncthreads();
        if (t < BK_SIZE) sscan[t] += tv;
        __syncthreads();
    }
    if (t < BK_SIZE) {
        int excl = sscan[t] - ldeg[t];
        int gpos = lo + excl;
        lcur[t] = gpos;
        int node = b * BK_SIZE + t;
        if (node < N) {
            rowptr[node] = gpos;
            dinv[node] = 1.0f / fmaxf((float)ldeg[t], 1.0f);
        }
    }
    __syncthreads();
    for (int e = lo + t; e < hi; e += 256) {
        unsigned p = packed[e];
        int l = (p >> 17) & (BK_SIZE - 1);
        int pos = atomicAdd(&lcur[l], 1);
        csr[pos] = (int)(p & 0x1FFFFu);
    }
}

// ---------------- Weight prep: Wx,Wy fp32 -> interleaved bf16 WcT + bias ----

__global__ __launch_bounds__(256) void wprep_kernel(
    const float* __restrict__ Wx, const float* __restrict__ bx,
    const float* __restrict__ Wy, const float* __restrict__ by,
    unsigned short* __restrict__ WcT, float* __restrict__ bc) {
    int t = blockIdx.x * blockDim.x + threadIdx.x;
    if (t < 192 * 128) {
        int cc = t >> 7;
        int k = t & 127;
        int h = cc >> 1;
        float w = (cc & 1) ? Wy[k * HDIM + h] : Wx[k * HDIM + h];
        WcT[cc * 128 + k] = (unsigned short)bf16_rne(w);
    }
    if (t < 192) {
        int h = t >> 1;
        bc[t] = (t & 1) ? by[h] : bx[h];
    }
}

// ---------------- Lift (MFMA): tanh(x @ [Wx|Wy] + b) ----------------

#define LW_STRIDE 136

__global__ __launch_bounds__(256) void lift_mfma_kernel(
    const float* __restrict__ x, const unsigned short* __restrict__ WcT,
    const float* __restrict__ bc, unsigned* __restrict__ S,
    unsigned* __restrict__ F, int N) {
    __shared__ unsigned short sW[192 * LW_STRIDE];  // 52224 B
    __shared__ float sBc[192];
    int t = threadIdx.x;

    {
        const unsigned* g = (const unsigned*)WcT;  // 192*64 uints
        unsigned* s = (unsigned*)sW;
        for (int i = t; i < 192 * 64; i += 256) {
            int cc = i >> 6;
            int kp = i & 63;
            s[cc * (LW_STRIDE / 2) + kp] = g[i];
        }
    }
    if (t < 192) sBc[t] = bc[t];
    __syncthreads();

    int wv = t >> 6;
    int lane = t & 63;
    int quad = lane >> 4;
    int m = lane & 15;
    int mbase = blockIdx.x * 64 + wv * 16;

    int anode = mbase + m;
    if (anode >= N) anode = N - 1;  // clamp; stores guarded
    const float* xrow = x + (size_t)anode * CIN;

    vfloat4 acc[12];
#pragma unroll
    for (int i = 0; i < 12; i++) acc[i] = (vfloat4){0.f, 0.f, 0.f, 0.f};

#pragma unroll
    for (int kt = 0; kt < 4; kt++) {
        int k0 = kt * 32 + quad * 8;
        float4 xa = *(const float4*)(xrow + k0);
        float4 xb = *(const float4*)(xrow + k0 + 4);
        uint4 ua;
        ua.x = pack_bf16_pair(xa.x, xa.y);
        ua.y = pack_bf16_pair(xa.z, xa.w);
        ua.z = pack_bf16_pair(xb.x, xb.y);
        ua.w = pack_bf16_pair(xb.z, xb.w);
        vshort8 a = *(vshort8*)&ua;
#pragma unroll
        for (int nt = 0; nt < 12; nt++) {
            vshort8 b = *(const vshort8*)&sW[(nt * 16 + m) * LW_STRIDE + k0];
            acc[nt] = __builtin_amdgcn_mfma_f32_16x16x32_bf16(a, b, acc[nt], 0, 0, 0);
        }
    }

    // C/D: row(node) = quad*4+reg, col(cc within tile) = lane&15
#pragma unroll
    for (int nt = 0; nt < 12; nt++) {
        int ccb = nt * 16 + m;
        float bco = sBc[ccb];
#pragma unroll
        for (int r = 0; r < 4; r++) {
            int node = mbase + quad * 4 + r;
            float v = tanhf(acc[nt][r] + bco);
            float v1 = __shfl_xor(v, 1);  // partner channel (m^1)
            unsigned u = (unsigned)(__builtin_amdgcn_cvt_pk_fp8_f32(v, v1, 0, false) & 0xffff);
            unsigned w = u | (((unsigned)__shfl_xor((int)u, 2)) << 16);
            unsigned hp = pack_f16_pair(v, v1);
            if (node < N) {
                if ((m & 1) == 0) S[(size_t)node * 96 + (ccb >> 1)] = hp;
                if ((m & 3) == 0) F[(size_t)node * 48 + (ccb >> 2)] = w;
            }
        }
    }
}

// ---------------- Layer: mean agg + LV Euler update ----------------
// 4 nodes per wave: group g = lane>>4 owns node, li = lane&15 owns channel
// pairs {3li, 3li+1, 3li+2} (= F uints 3li..3li+2, 12 B dwordx3 per gathered
// row). CSR indices loaded 16-wide per group, broadcast via __shfl within
// the group. 4-edge manual unroll keeps 4 dwordx3 gathers in flight.

__global__ __launch_bounds__(256) void layer_kernel(
    const unsigned* __restrict__ F, const unsigned* __restrict__ S,
    unsigned* __restrict__ Sn, unsigned* __restrict__ Fn,
    const int* __restrict__ rowptr, const int* __restrict__ csr,
    const float* __restrict__ deg_inv,
    const float* __restrict__ alpha, const float* __restrict__ beta,
    const float* __restrict__ gamma, const float* __restrict__ delta,
    int N) {
    int wave = threadIdx.x >> 6;
    int lane = threadIdx.x & 63;
    int li = lane & 15;
    int gbase = lane & 48;  // group base lane (g*16)

    int node = (blockIdx.x * 4 + wave) * 4 + (lane >> 4);
    bool nvalid = node < N;
    int nclamp = nvalid ? node : N - 1;
    int beg = rowptr[nclamp];
    int cnt = nvalid ? (rowptr[nclamp + 1] - beg) : 0;

    // ac[4k+{0,1,2,3}] = sum X[2p], Y[2p], X[2p+1], Y[2p+1] for pair p=3li+k
    float ac[12];
#pragma unroll
    for (int i = 0; i < 12; i++) ac[i] = 0.f;

#define UNP(u, k)                                                           \
    do {                                                                    \
        vfloat2 p0 = __builtin_amdgcn_cvt_pk_f32_fp8((int)(u), false);      \
        vfloat2 p1 = __builtin_amdgcn_cvt_pk_f32_fp8((int)(u), true);       \
        ac[4*(k)+0] += p0.x; ac[4*(k)+1] += p0.y;                           \
        ac[4*(k)+2] += p1.x; ac[4*(k)+3] += p1.y;                           \
    } while (0)
#define UNP3(u)  do { UNP((u).x, 0); UNP((u).y, 1); UNP((u).z, 2); } while (0)

    for (int base = 0; base < cnt; base += 16) {
        int m = min(16, cnt - base);
        int sidx = (li < m) ? csr[beg + base + li] : 0;
        int j = 0;
        for (; j + 4 <= m; j += 4) {
            int s0 = __shfl(sidx, gbase + j);
            int s1 = __shfl(sidx, gbase + j + 1);
            int s2 = __shfl(sidx, gbase + j + 2);
            int s3 = __shfl(sidx, gbase + j + 3);
            uint3 u0 = ((const uint3*)(F + (size_t)s0 * 48))[li];
            uint3 u1 = ((const uint3*)(F + (size_t)s1 * 48))[li];
            uint3 u2 = ((const uint3*)(F + (size_t)s2 * 48))[li];
            uint3 u3 = ((const uint3*)(F + (size_t)s3 * 48))[li];
            UNP3(u0); UNP3(u1); UNP3(u2); UNP3(u3);
        }
        for (; j < m; j++) {
            int s = __shfl(sidx, gbase + j);
            uint3 u = ((const uint3*)(F + (size_t)s * 48))[li];
            UNP3(u);
        }
    }
#undef UNP3
#undef UNP

    if (!nvalid) return;

    float dinv = deg_inv[nclamp];
    const uint2* srow = (const uint2*)(S + (size_t)node * 96);
    unsigned so[6];
    unsigned fo[3];
#pragma unroll
    for (int k = 0; k < 3; k++) {
        int p = 3 * li + k;
        float2 a2 = ((const float2*)alpha)[p];
        float2 b2 = ((const float2*)beta)[p];
        float2 g2 = ((const float2*)gamma)[p];
        float2 d2 = ((const float2*)delta)[p];
        uint2 su = srow[p];
        float vx = f16_lo(su.x), vy = f16_hi(su.x);
        float vz = f16_lo(su.y), vw = f16_hi(su.y);
        float ox = vx + DTC * vx * (a2.x - b2.x * (ac[4*k+1] * dinv));
        float oy = vy + DTC * vy * (-g2.x + d2.x * (ac[4*k+0] * dinv));
        float oz = vz + DTC * vz * (a2.y - b2.y * (ac[4*k+3] * dinv));
        float ow = vw + DTC * vw * (-g2.y + d2.y * (ac[4*k+2] * dinv));
        so[2*k+0] = pack_f16_pair(ox, oy);
        so[2*k+1] = pack_f16_pair(oz, ow);
        fo[k] = pack_fp8_quad(ox, oy, oz, ow);
    }
    {
        uint3 t0 = {so[0], so[1], so[2]};
        uint3 t1 = {so[3], so[4], so[5]};
        ((uint3*)(Sn + (size_t)node * 96))[2*li+0] = t0;
        ((uint3*)(Sn + (size_t)node * 96))[2*li+1] = t1;
    }
    if (Fn) {
        uint3 tf = {fo[0], fo[1], fo[2]};
        ((uint3*)(Fn + (size_t)node * 48))[li] = tf;
    }
}

// ---------------- Readout: out = [X,Y] @ Wr + br via f16 MFMA ----------------

#define WG_STRIDE 200

__global__ __launch_bounds__(256) void readout_mfma_kernel(
    const unsigned short* __restrict__ sh, const float* __restrict__ Wr,
    const float* __restrict__ br, float* __restrict__ out, int N) {
    __shared__ unsigned short sW[48 * WG_STRIDE];
    __shared__ float sB[48];
    int t = threadIdx.x;

    for (int i = t; i < 48 * 192; i += 256) {
        int n = i / 192;
        int kk = i - n * 192;
        int h = kk >> 1;
        float w = 0.f;
        if (n < COUT) w = (kk & 1) ? Wr[(HDIM + h) * COUT + n] : Wr[h * COUT + n];
        sW[n * WG_STRIDE + kk] = __half_as_ushort(__float2half_rn(w));
    }
    if (t < 48) sB[t] = (t < COUT) ? br[t] : 0.f;
    __syncthreads();

    int wv = t >> 6;
    int lane = t & 63;
    int quad = lane >> 4;
    int m = lane & 15;
    int mbase = blockIdx.x * 64 + wv * 16;

    int anode = mbase + m;
    if (anode >= N) anode = N - 1;
    const unsigned short* arow = sh + (size_t)anode * 192;

    vfloat4 acc0 = {0.f, 0.f, 0.f, 0.f};
    vfloat4 acc1 = {0.f, 0.f, 0.f, 0.f};
    vfloat4 acc2 = {0.f, 0.f, 0.f, 0.f};

#pragma unroll
    for (int kt = 0; kt < 6; kt++) {
        int k0 = kt * 32 + quad * 8;
        vshort8 a = *(const vshort8*)(arow + k0);
        vshort8 b0 = *(const vshort8*)&sW[(0 * 16 + m) * WG_STRIDE + k0];
        vshort8 b1 = *(const vshort8*)&sW[(1 * 16 + m) * WG_STRIDE + k0];
        vshort8 b2 = *(const vshort8*)&sW[(2 * 16 + m) * WG_STRIDE + k0];
        acc0 = __builtin_amdgcn_mfma_f32_16x16x32_f16(a, b0, acc0, 0, 0, 0);
        acc1 = __builtin_amdgcn_mfma_f32_16x16x32_f16(a, b1, acc1, 0, 0, 0);
        acc2 = __builtin_amdgcn_mfma_f32_16x16x32_f16(a, b2, acc2, 0, 0, 0);
    }

    float bo0 = sB[m];
    float bo1 = sB[16 + m];
    float bo2 = (m < 8) ? sB[32 + m] : 0.f;
#pragma unroll
    for (int r = 0; r < 4; r++) {
        int node = mbase + quad * 4 + r;
        if (node < N) {
            float* orow = out + (size_t)node * COUT;
            orow[m] = acc0[r] + bo0;
            orow[16 + m] = acc1[r] + bo1;
            if (m < 8) orow[32 + m] = acc2[r] + bo2;
        }
    }
}

// ---------------- launch ----------------

extern "C" void kernel_launch(void* const* d_in, const int* in_sizes, int n_in,
                              void* d_out, int out_size, void* d_ws, size_t ws_size,
                              hipStream_t stream) {
    const float* x     = (const float*)d_in[0];
    const int*   ei    = (const int*)d_in[1];
    const float* Wx    = (const float*)d_in[2];
    const float* bx    = (const float*)d_in[3];
    const float* Wy    = (const float*)d_in[4];
    const float* by    = (const float*)d_in[5];
    const float* alpha = (const float*)d_in[6];
    const float* beta  = (const float*)d_in[7];
    const float* gamma = (const float*)d_in[8];
    const float* delta = (const float*)d_in[9];
    const float* Wr    = (const float*)d_in[10];
    const float* br    = (const float*)d_in[11];

    const int N = in_sizes[0] / CIN;
    const int E = in_sizes[1] / 2;
    const int NB = (N + BK_SIZE - 1) >> BK_SHIFT;     // 391 for N=50000 (<=512)
    const int nchunk = (E + EPB - 1) / EPB;           // 196 for E=800000

    char* ws = (char*)d_ws;
    size_t off = 0;
    auto alloc = [&](size_t bytes) -> void* {
        off = (off + 255) & ~(size_t)255;
        void* p = ws + off;
        off += bytes;
        return p;
    };
    int* ghist     = (int*)alloc((size_t)NB * sizeof(int));
    int* bbase     = (int*)alloc((size_t)(NB + 1) * sizeof(int));
    int* bcursor   = (int*)alloc((size_t)NB * sizeof(int));
    unsigned* pckd = (unsigned*)alloc((size_t)E * sizeof(unsigned));
    int* rowptr    = (int*)alloc((size_t)(N + 1) * sizeof(int));
    int* csr       = (int*)alloc((size_t)E * sizeof(int));
    float* dinv    = (float*)alloc((size_t)N * sizeof(float));
    unsigned* Sa   = (unsigned*)alloc((size_t)N * 96 * sizeof(unsigned));   // fp16 state
    unsigned* Sb   = (unsigned*)alloc((size_t)N * 96 * sizeof(unsigned));
    unsigned* Fa   = (unsigned*)alloc((size_t)N * 48 * sizeof(unsigned));   // fp8 mirror
    unsigned* Fb   = (unsigned*)alloc((size_t)N * 48 * sizeof(unsigned));
    unsigned short* WcT = (unsigned short*)alloc((size_t)192 * 128 * sizeof(unsigned short));
    float* bc      = (float*)alloc((size_t)192 * sizeof(float));
    (void)ws_size;

    const int* e_src = ei;
    const int* e_dst = ei + E;

    hipMemsetAsync(ghist, 0, (size_t)NB * sizeof(int), stream);

    bhist_kernel<<<nchunk, 256, 0, stream>>>(e_dst, ghist, E, NB);
    bscan_kernel<<<1, 512, 0, stream>>>(ghist, bbase, bcursor, rowptr, NB, N, E);
    bscatter_kernel<<<nchunk, 256, 0, stream>>>(e_src, e_dst, bcursor, pckd, E, NB);
    bcsr_kernel<<<NB, 256, 0, stream>>>(pckd, bbase, rowptr, dinv, csr, N, NB);

    wprep_kernel<<<(192 * 128 + 255) / 256, 256, 0, stream>>>(Wx, bx, Wy, by, WcT, bc);
    lift_mfma_kernel<<<(N + 63) / 64, 256, 0, stream>>>(x, WcT, bc, Sa, Fa, N);

    const unsigned* Sc = Sa;
    unsigned* Snx = Sb;
    const unsigned* Fc = Fa;
    unsigned* Fnx = Fb;
    for (int l = 0; l < NLAYER; l++) {
        bool last = (l == NLAYER - 1);
        layer_kernel<<<(N + 15) / 16, 256, 0, stream>>>(
            Fc, Sc, Snx, last ? (unsigned*)nullptr : Fnx,
            rowptr, csr, dinv,
            alpha + l * HDIM, beta + l * HDIM, gamma + l * HDIM, delta + l * HDIM, N);
        const unsigned* ts = Sc; Sc = Snx; Snx = (unsigned*)ts;
        const unsigned* tf = Fc; Fc = Fnx; Fnx = (unsigned*)tf;
    }

    readout_mfma_kernel<<<(N + 63) / 64, 256, 0, stream>>>(
        (const unsigned short*)Sc, Wr, br, (float*)d_out, N);
}

// Round 10
// 313.928 us; speedup vs baseline: 3.4102x; 1.0317x over previous
//
#include <hip/hip_runtime.h>
#include <hip/hip_bf16.h>
#include <hip/hip_fp16.h>

// PPGNN: lift -> 5x (mean-aggregate + Lotka-Volterra Euler step) -> readout
// N=50000, E=800000, C_IN=128, H=96, C_OUT=40, L=5, DT=0.05
//
// Master state S: fp16, row = 192 halfs = 96 uints (cc even = X[cc/2], odd
// = Y[cc/2]). fp8 e4m3 mirror F (uint = 4 fp8 for channel pair {2l,2l+1};
// row 48 uints = 192 B) is what layer gathers read. Readout consumes the
// final fp16 state directly via f16 MFMA. Lift + readout are MFMA GEMMs;
// CSR build is the bucketed atomic-light build.
// Lift epilogue: LDS transpose -> coalesced dwordx4 S stores + dwordx2 F
// stores (was 1.4x partial-line write amplification), fast exp-based tanh.

#define HDIM 96
#define CIN 128
#define COUT 40
#define NLAYER 5
#define DTC 0.05f

#define BK_SHIFT 7
#define BK_SIZE 128
#define EPB 4096   // edges per block in bucket hist/scatter

typedef float  vfloat2 __attribute__((ext_vector_type(2)));
typedef float  vfloat4 __attribute__((ext_vector_type(4)));
typedef short  vshort8 __attribute__((ext_vector_type(8)));

__device__ __forceinline__ unsigned bf16_rne(float f) {
    unsigned u = __float_as_uint(f);
    return (u + 0x7fffu + ((u >> 16) & 1u)) >> 16;
}

__device__ __forceinline__ unsigned pack_bf16_pair(float xf, float yf) {
    return bf16_rne(xf) | (bf16_rne(yf) << 16);
}

__device__ __forceinline__ unsigned pack_f16_pair(float a, float b) {
    unsigned ha = (unsigned)__half_as_ushort(__float2half_rn(a));
    unsigned hb = (unsigned)__half_as_ushort(__float2half_rn(b));
    return ha | (hb << 16);
}

__device__ __forceinline__ float f16_lo(unsigned u) {
    return __half2float(__ushort_as_half((unsigned short)(u & 0xffffu)));
}
__device__ __forceinline__ float f16_hi(unsigned u) {
    return __half2float(__ushort_as_half((unsigned short)(u >> 16)));
}

__device__ __forceinline__ unsigned pack_fp8_quad(float x0, float y0, float x1, float y1) {
    int lo = __builtin_amdgcn_cvt_pk_fp8_f32(x0, y0, 0, false);
    int full = __builtin_amdgcn_cvt_pk_fp8_f32(x1, y1, lo, true);
    return (unsigned)full;
}

// tanh via hw exp/rcp: 1 - 2/(e^{2x}+1). ~1e-7 err, +/-inf-safe.
__device__ __forceinline__ float fast_tanh(float x) {
    float e = __expf(2.0f * x);
    return 1.0f - 2.0f * __builtin_amdgcn_rcpf(e + 1.0f);
}

// ---------------- CSR build (bucketed, atomic-light) ----------------

__global__ __launch_bounds__(256) void bhist_kernel(const int* __restrict__ dst,
                                                    int* __restrict__ ghist, int E, int NB) {
    __shared__ int h[512];
    for (int i = threadIdx.x; i < NB; i += 256) h[i] = 0;
    __syncthreads();
    int base = blockIdx.x * EPB;
    int end = min(E, base + EPB);
    for (int e = base + threadIdx.x; e < end; e += 256)
        atomicAdd(&h[dst[e] >> BK_SHIFT], 1);
    __syncthreads();
    for (int i = threadIdx.x; i < NB; i += 256)
        if (h[i]) atomicAdd(&ghist[i], h[i]);
}

__global__ void bscan_kernel(const int* __restrict__ ghist, int* __restrict__ bbase,
                             int* __restrict__ bcursor, int* __restrict__ rowptr,
                             int NB, int N, int E) {
    __shared__ int sd[512];
    int t = threadIdx.x;
    int v = (t < NB) ? ghist[t] : 0;
    sd[t] = v;
    __syncthreads();
    for (int off = 1; off < 512; off <<= 1) {
        int tv = (t >= off) ? sd[t - off] : 0;
        __syncthreads();
        sd[t] += tv;
        __syncthreads();
    }
    if (t < NB) {
        int b = sd[t] - v;  // exclusive
        bbase[t] = b;
        bcursor[t] = b;
    }
    if (t == 0) { bbase[NB] = E; rowptr[N] = E; }
}

__global__ __launch_bounds__(256) void bscatter_kernel(
    const int* __restrict__ src, const int* __restrict__ dst,
    int* __restrict__ bcursor, unsigned* __restrict__ packed, int E, int NB) {
    __shared__ int h[512];
    __shared__ int cur[512];
    for (int i = threadIdx.x; i < NB; i += 256) h[i] = 0;
    __syncthreads();
    int base = blockIdx.x * EPB;
    int end = min(E, base + EPB);
    for (int e = base + threadIdx.x; e < end; e += 256)
        atomicAdd(&h[dst[e] >> BK_SHIFT], 1);
    __syncthreads();
    for (int i = threadIdx.x; i < NB; i += 256)
        cur[i] = h[i] ? atomicAdd(&bcursor[i], h[i]) : 0;
    __syncthreads();
    for (int e = base + threadIdx.x; e < end; e += 256) {
        int d = dst[e];
        int b = d >> BK_SHIFT;
        int pos = atomicAdd(&cur[b], 1);
        packed[pos] = (unsigned)src[e] | ((unsigned)(d & (BK_SIZE - 1)) << 17);
    }
}

__global__ __launch_bounds__(256) void bcsr_kernel(
    const unsigned* __restrict__ packed, const int* __restrict__ bbase,
    int* __restrict__ rowptr, float* __restrict__ dinv, int* __restrict__ csr,
    int N, int NB) {
    __shared__ int ldeg[BK_SIZE];
    __shared__ int sscan[BK_SIZE];
    __shared__ int lcur[BK_SIZE];
    int b = blockIdx.x;
    int t = threadIdx.x;
    int lo = bbase[b], hi = bbase[b + 1];
    if (t < BK_SIZE) ldeg[t] = 0;
    __syncthreads();
    for (int e = lo + t; e < hi; e += 256)
        atomicAdd(&ldeg[(packed[e] >> 17) & (BK_SIZE - 1)], 1);
    __syncthreads();
    if (t < BK_SIZE) sscan[t] = ldeg[t];
    __syncthreads();
    for (int off = 1; off < BK_SIZE; off <<= 1) {
        int tv = (t < BK_SIZE && t >= off) ? sscan[t - off] : 0;
        __syncthreads();
        if (t < BK_SIZE) sscan[t] += tv;
        __syncthreads();
    }
    if (t < BK_SIZE) {
        int excl = sscan[t] - ldeg[t];
        int gpos = lo + excl;
        lcur[t] = gpos;
        int node = b * BK_SIZE + t;
        if (node < N) {
            rowptr[node] = gpos;
            dinv[node] = 1.0f / fmaxf((float)ldeg[t], 1.0f);
        }
    }
    __syncthreads();
    for (int e = lo + t; e < hi; e += 256) {
        unsigned p = packed[e];
        int l = (p >> 17) & (BK_SIZE - 1);
        int pos = atomicAdd(&lcur[l], 1);
        csr[pos] = (int)(p & 0x1FFFFu);
    }
}

// ---------------- Weight prep: Wx,Wy fp32 -> interleaved bf16 WcT + bias ----

__global__ __launch_bounds__(256) void wprep_kernel(
    const float* __restrict__ Wx, const float* __restrict__ bx,
    const float* __restrict__ Wy, const float* __restrict__ by,
    unsigned short* __restrict__ WcT, float* __restrict__ bc) {
    int t = blockIdx.x * blockDim.x + threadIdx.x;
    if (t < 192 * 128) {
        int cc = t >> 7;
        int k = t & 127;
        int h = cc >> 1;
        float w = (cc & 1) ? Wy[k * HDIM + h] : Wx[k * HDIM + h];
        WcT[cc * 128 + k] = (unsigned short)bf16_rne(w);
    }
    if (t < 192) {
        int h = t >> 1;
        bc[t] = (t & 1) ? by[h] : bx[h];
    }
}

// ---------------- Lift (MFMA): tanh(x @ [Wx|Wy] + b) ----------------
// MFMA phase uses sW in LDS; epilogue reuses the same LDS as a
// [64 nodes][200-ushort] fp16 tile, then stores S (dwordx4) and F (dwordx2)
// fully coalesced.

#define LW_STRIDE 136
#define TILE_STRIDE 200  // ushorts: 400 B rows, 16B-aligned

__global__ __launch_bounds__(256) void lift_mfma_kernel(
    const float* __restrict__ x, const unsigned short* __restrict__ WcT,
    const float* __restrict__ bc, unsigned* __restrict__ S,
    unsigned* __restrict__ F, int N) {
    __shared__ __align__(16) char smem[192 * LW_STRIDE * 2];  // 52224 B
    __shared__ float sBc[192];
    unsigned short* sW = (unsigned short*)smem;
    unsigned short* tile = (unsigned short*)smem;  // reused after barrier
    int t = threadIdx.x;

    {
        const unsigned* g = (const unsigned*)WcT;  // 192*64 uints
        unsigned* s = (unsigned*)sW;
        for (int i = t; i < 192 * 64; i += 256) {
            int cc = i >> 6;
            int kp = i & 63;
            s[cc * (LW_STRIDE / 2) + kp] = g[i];
        }
    }
    if (t < 192) sBc[t] = bc[t];
    __syncthreads();

    int wv = t >> 6;
    int lane = t & 63;
    int quad = lane >> 4;
    int m = lane & 15;
    int mbase = blockIdx.x * 64 + wv * 16;

    int anode = mbase + m;
    if (anode >= N) anode = N - 1;  // clamp; stores guarded
    const float* xrow = x + (size_t)anode * CIN;

    vfloat4 acc[12];
#pragma unroll
    for (int i = 0; i < 12; i++) acc[i] = (vfloat4){0.f, 0.f, 0.f, 0.f};

#pragma unroll
    for (int kt = 0; kt < 4; kt++) {
        int k0 = kt * 32 + quad * 8;
        float4 xa = *(const float4*)(xrow + k0);
        float4 xb = *(const float4*)(xrow + k0 + 4);
        uint4 ua;
        ua.x = pack_bf16_pair(xa.x, xa.y);
        ua.y = pack_bf16_pair(xa.z, xa.w);
        ua.z = pack_bf16_pair(xb.x, xb.y);
        ua.w = pack_bf16_pair(xb.z, xb.w);
        vshort8 a = *(vshort8*)&ua;
#pragma unroll
        for (int nt = 0; nt < 12; nt++) {
            vshort8 b = *(const vshort8*)&sW[(nt * 16 + m) * LW_STRIDE + k0];
            acc[nt] = __builtin_amdgcn_mfma_f32_16x16x32_bf16(a, b, acc[nt], 0, 0, 0);
        }
    }

    // ---- epilogue phase 1: tanh + fp16 into LDS tile ----
    __syncthreads();  // all waves done reading sW
#pragma unroll
    for (int nt = 0; nt < 12; nt++) {
        int ccb = nt * 16 + m;
        float bco = sBc[ccb];
#pragma unroll
        for (int r = 0; r < 4; r++) {
            int nl = wv * 16 + quad * 4 + r;  // local node 0..63
            float v = fast_tanh(acc[nt][r] + bco);
            tile[nl * TILE_STRIDE + ccb] = __half_as_ushort(__float2half_rn(v));
        }
    }
    __syncthreads();

    // ---- epilogue phase 2: coalesced S (uint4) + F (uint2) stores ----
    int nbase = blockIdx.x * 64;
#pragma unroll
    for (int i = 0; i < 6; i++) {
        int idx = i * 256 + t;       // 0..1535
        int nl = idx / 24;           // local node (24 uint4 per 96-dword row)
        int pos = idx - nl * 24;
        int node = nbase + nl;
        uint4 u = *(const uint4*)&tile[nl * TILE_STRIDE + pos * 8];
        if (node < N) {
            *(uint4*)(S + (size_t)node * 96 + pos * 4) = u;
            float f0 = f16_lo(u.x), f1 = f16_hi(u.x);
            float f2 = f16_lo(u.y), f3 = f16_hi(u.y);
            float f4 = f16_lo(u.z), f5 = f16_hi(u.z);
            float f6 = f16_lo(u.w), f7 = f16_hi(u.w);
            uint2 fq = make_uint2(pack_fp8_quad(f0, f1, f2, f3),
                                  pack_fp8_quad(f4, f5, f6, f7));
            *(uint2*)(F + (size_t)node * 48 + pos * 2) = fq;
        }
    }
}

// ---------------- Layer: mean agg + LV Euler update ----------------
// 4 nodes per wave: group g = lane>>4 owns node, li = lane&15 owns channel
// pairs {3li, 3li+1, 3li+2} (= F uints 3li..3li+2, 12 B dwordx3 per gathered
// row). CSR indices loaded 16-wide per group, broadcast via __shfl within
// the group. 4-edge manual unroll keeps 4 dwordx3 gathers in flight.

__global__ __launch_bounds__(256) void layer_kernel(
    const unsigned* __restrict__ F, const unsigned* __restrict__ S,
    unsigned* __restrict__ Sn, unsigned* __restrict__ Fn,
    const int* __restrict__ rowptr, const int* __restrict__ csr,
    const float* __restrict__ deg_inv,
    const float* __restrict__ alpha, const float* __restrict__ beta,
    const float* __restrict__ gamma, const float* __restrict__ delta,
    int N) {
    int wave = threadIdx.x >> 6;
    int lane = threadIdx.x & 63;
    int li = lane & 15;
    int gbase = lane & 48;  // group base lane (g*16)

    int node = (blockIdx.x * 4 + wave) * 4 + (lane >> 4);
    bool nvalid = node < N;
    int nclamp = nvalid ? node : N - 1;
    int beg = rowptr[nclamp];
    int cnt = nvalid ? (rowptr[nclamp + 1] - beg) : 0;

    // ac[4k+{0,1,2,3}] = sum X[2p], Y[2p], X[2p+1], Y[2p+1] for pair p=3li+k
    float ac[12];
#pragma unroll
    for (int i = 0; i < 12; i++) ac[i] = 0.f;

#define UNP(u, k)                                                           \
    do {                                                                    \
        vfloat2 p0 = __builtin_amdgcn_cvt_pk_f32_fp8((int)(u), false);      \
        vfloat2 p1 = __builtin_amdgcn_cvt_pk_f32_fp8((int)(u), true);       \
        ac[4*(k)+0] += p0.x; ac[4*(k)+1] += p0.y;                           \
        ac[4*(k)+2] += p1.x; ac[4*(k)+3] += p1.y;                           \
    } while (0)
#define UNP3(u)  do { UNP((u).x, 0); UNP((u).y, 1); UNP((u).z, 2); } while (0)

    for (int base = 0; base < cnt; base += 16) {
        int m = min(16, cnt - base);
        int sidx = (li < m) ? csr[beg + base + li] : 0;
        int j = 0;
        for (; j + 4 <= m; j += 4) {
            int s0 = __shfl(sidx, gbase + j);
            int s1 = __shfl(sidx, gbase + j + 1);
            int s2 = __shfl(sidx, gbase + j + 2);
            int s3 = __shfl(sidx, gbase + j + 3);
            uint3 u0 = ((const uint3*)(F + (size_t)s0 * 48))[li];
            uint3 u1 = ((const uint3*)(F + (size_t)s1 * 48))[li];
            uint3 u2 = ((const uint3*)(F + (size_t)s2 * 48))[li];
            uint3 u3 = ((const uint3*)(F + (size_t)s3 * 48))[li];
            UNP3(u0); UNP3(u1); UNP3(u2); UNP3(u3);
        }
        for (; j < m; j++) {
            int s = __shfl(sidx, gbase + j);
            uint3 u = ((const uint3*)(F + (size_t)s * 48))[li];
            UNP3(u);
        }
    }
#undef UNP3
#undef UNP

    if (!nvalid) return;

    float dinv = deg_inv[nclamp];
    const uint2* srow = (const uint2*)(S + (size_t)node * 96);
    unsigned so[6];
    unsigned fo[3];
#pragma unroll
    for (int k = 0; k < 3; k++) {
        int p = 3 * li + k;
        float2 a2 = ((const float2*)alpha)[p];
        float2 b2 = ((const float2*)beta)[p];
        float2 g2 = ((const float2*)gamma)[p];
        float2 d2 = ((const float2*)delta)[p];
        uint2 su = srow[p];
        float vx = f16_lo(su.x), vy = f16_hi(su.x);
        float vz = f16_lo(su.y), vw = f16_hi(su.y);
        float ox = vx + DTC * vx * (a2.x - b2.x * (ac[4*k+1] * dinv));
        float oy = vy + DTC * vy * (-g2.x + d2.x * (ac[4*k+0] * dinv));
        float oz = vz + DTC * vz * (a2.y - b2.y * (ac[4*k+3] * dinv));
        float ow = vw + DTC * vw * (-g2.y + d2.y * (ac[4*k+2] * dinv));
        so[2*k+0] = pack_f16_pair(ox, oy);
        so[2*k+1] = pack_f16_pair(oz, ow);
        fo[k] = pack_fp8_quad(ox, oy, oz, ow);
    }
    {
        uint3 t0 = {so[0], so[1], so[2]};
        uint3 t1 = {so[3], so[4], so[5]};
        ((uint3*)(Sn + (size_t)node * 96))[2*li+0] = t0;
        ((uint3*)(Sn + (size_t)node * 96))[2*li+1] = t1;
    }
    if (Fn) {
        uint3 tf = {fo[0], fo[1], fo[2]};
        ((uint3*)(Fn + (size_t)node * 48))[li] = tf;
    }
}

// ---------------- Readout: out = [X,Y] @ Wr + br via f16 MFMA ----------------

#define WG_STRIDE 200

__global__ __launch_bounds__(256) void readout_mfma_kernel(
    const unsigned short* __restrict__ sh, const float* __restrict__ Wr,
    const float* __restrict__ br, float* __restrict__ out, int N) {
    __shared__ unsigned short sW[48 * WG_STRIDE];
    __shared__ float sB[48];
    int t = threadIdx.x;

    for (int i = t; i < 48 * 192; i += 256) {
        int n = i / 192;
        int kk = i - n * 192;
        int h = kk >> 1;
        float w = 0.f;
        if (n < COUT) w = (kk & 1) ? Wr[(HDIM + h) * COUT + n] : Wr[h * COUT + n];
        sW[n * WG_STRIDE + kk] = __half_as_ushort(__float2half_rn(w));
    }
    if (t < 48) sB[t] = (t < COUT) ? br[t] : 0.f;
    __syncthreads();

    int wv = t >> 6;
    int lane = t & 63;
    int quad = lane >> 4;
    int m = lane & 15;
    int mbase = blockIdx.x * 64 + wv * 16;

    int anode = mbase + m;
    if (anode >= N) anode = N - 1;
    const unsigned short* arow = sh + (size_t)anode * 192;

    vfloat4 acc0 = {0.f, 0.f, 0.f, 0.f};
    vfloat4 acc1 = {0.f, 0.f, 0.f, 0.f};
    vfloat4 acc2 = {0.f, 0.f, 0.f, 0.f};

#pragma unroll
    for (int kt = 0; kt < 6; kt++) {
        int k0 = kt * 32 + quad * 8;
        vshort8 a = *(const vshort8*)(arow + k0);
        vshort8 b0 = *(const vshort8*)&sW[(0 * 16 + m) * WG_STRIDE + k0];
        vshort8 b1 = *(const vshort8*)&sW[(1 * 16 + m) * WG_STRIDE + k0];
        vshort8 b2 = *(const vshort8*)&sW[(2 * 16 + m) * WG_STRIDE + k0];
        acc0 = __builtin_amdgcn_mfma_f32_16x16x32_f16(a, b0, acc0, 0, 0, 0);
        acc1 = __builtin_amdgcn_mfma_f32_16x16x32_f16(a, b1, acc1, 0, 0, 0);
        acc2 = __builtin_amdgcn_mfma_f32_16x16x32_f16(a, b2, acc2, 0, 0, 0);
    }

    float bo0 = sB[m];
    float bo1 = sB[16 + m];
    float bo2 = (m < 8) ? sB[32 + m] : 0.f;
#pragma unroll
    for (int r = 0; r < 4; r++) {
        int node = mbase + quad * 4 + r;
        if (node < N) {
            float* orow = out + (size_t)node * COUT;
            orow[m] = acc0[r] + bo0;
            orow[16 + m] = acc1[r] + bo1;
            if (m < 8) orow[32 + m] = acc2[r] + bo2;
        }
    }
}

// ---------------- launch ----------------

extern "C" void kernel_launch(void* const* d_in, const int* in_sizes, int n_in,
                              void* d_out, int out_size, void* d_ws, size_t ws_size,
                              hipStream_t stream) {
    const float* x     = (const float*)d_in[0];
    const int*   ei    = (const int*)d_in[1];
    const float* Wx    = (const float*)d_in[2];
    const float* bx    = (const float*)d_in[3];
    const float* Wy    = (const float*)d_in[4];
    const float* by    = (const float*)d_in[5];
    const float* alpha = (const float*)d_in[6];
    const float* beta  = (const float*)d_in[7];
    const float* gamma = (const float*)d_in[8];
    const float* delta = (const float*)d_in[9];
    const float* Wr    = (const float*)d_in[10];
    const float* br    = (const float*)d_in[11];

    const int N = in_sizes[0] / CIN;
    const int E = in_sizes[1] / 2;
    const int NB = (N + BK_SIZE - 1) >> BK_SHIFT;     // 391 for N=50000 (<=512)
    const int nchunk = (E + EPB - 1) / EPB;           // 196 for E=800000

    char* ws = (char*)d_ws;
    size_t off = 0;
    auto alloc = [&](size_t bytes) -> void* {
        off = (off + 255) & ~(size_t)255;
        void* p = ws + off;
        off += bytes;
        return p;
    };
    int* ghist     = (int*)alloc((size_t)NB * sizeof(int));
    int* bbase     = (int*)alloc((size_t)(NB + 1) * sizeof(int));
    int* bcursor   = (int*)alloc((size_t)NB * sizeof(int));
    unsigned* pckd = (unsigned*)alloc((size_t)E * sizeof(unsigned));
    int* rowptr    = (int*)alloc((size_t)(N + 1) * sizeof(int));
    int* csr       = (int*)alloc((size_t)E * sizeof(int));
    float* dinv    = (float*)alloc((size_t)N * sizeof(float));
    unsigned* Sa   = (unsigned*)alloc((size_t)N * 96 * sizeof(unsigned));   // fp16 state
    unsigned* Sb   = (unsigned*)alloc((size_t)N * 96 * sizeof(unsigned));
    unsigned* Fa   = (unsigned*)alloc((size_t)N * 48 * sizeof(unsigned));   // fp8 mirror
    unsigned* Fb   = (unsigned*)alloc((size_t)N * 48 * sizeof(unsigned));
    unsigned short* WcT = (unsigned short*)alloc((size_t)192 * 128 * sizeof(unsigned short));
    float* bc      = (float*)alloc((size_t)192 * sizeof(float));
    (void)ws_size;

    const int* e_src = ei;
    const int* e_dst = ei + E;

    hipMemsetAsync(ghist, 0, (size_t)NB * sizeof(int), stream);

    bhist_kernel<<<nchunk, 256, 0, stream>>>(e_dst, ghist, E, NB);
    bscan_kernel<<<1, 512, 0, stream>>>(ghist, bbase, bcursor, rowptr, NB, N, E);
    bscatter_kernel<<<nchunk, 256, 0, stream>>>(e_src, e_dst, bcursor, pckd, E, NB);
    bcsr_kernel<<<NB, 256, 0, stream>>>(pckd, bbase, rowptr, dinv, csr, N, NB);

    wprep_kernel<<<(192 * 128 + 255) / 256, 256, 0, stream>>>(Wx, bx, Wy, by, WcT, bc);
    lift_mfma_kernel<<<(N + 63) / 64, 256, 0, stream>>>(x, WcT, bc, Sa, Fa, N);

    const unsigned* Sc = Sa;
    unsigned* Snx = Sb;
    const unsigned* Fc = Fa;
    unsigned* Fnx = Fb;
    for (int l = 0; l < NLAYER; l++) {
        bool last = (l == NLAYER - 1);
        layer_kernel<<<(N + 15) / 16, 256, 0, stream>>>(
            Fc, Sc, Snx, last ? (unsigned*)nullptr : Fnx,
            rowptr, csr, dinv,
            alpha + l * HDIM, beta + l * HDIM, gamma + l * HDIM, delta + l * HDIM, N);
        const unsigned* ts = Sc; Sc = Snx; Snx = (unsigned*)ts;
        const unsigned* tf = Fc; Fc = Fnx; Fnx = (unsigned*)tf;
    }

    readout_mfma_kernel<<<(N + 63) / 64, 256, 0, stream>>>(
        (const unsigned short*)Sc, Wr, br, (float*)d_out, N);
}